// Round 4
// baseline (595.263 us; speedup 1.0000x reference)
//
#include <hip/hip_runtime.h>
#include <hip/hip_bf16.h>
#include <stdint.h>

#define BATCH 4
#define SEQ   4096          // 64*64 spatial
#define CH    512
#define NGRP  32
#define GEPS  1e-6f

typedef short  short8  __attribute__((ext_vector_type(8)));
typedef float  floatx4 __attribute__((ext_vector_type(4)));

static __device__ __forceinline__ short bf16b(float f) {
    __hip_bfloat16 h = __float2bfloat16(f);
    return __builtin_bit_cast(short, h);
}
static __device__ __forceinline__ float bf2f(short s) {
    unsigned u = ((unsigned)(unsigned short)s) << 16;
    return __builtin_bit_cast(float, u);
}

// async global->LDS, 16B per lane. LDS dest = wave-uniform base + lane*16.
static __device__ __forceinline__ void dma16(const void* g, void* l) {
    __builtin_amdgcn_global_load_lds(
        (const __attribute__((address_space(1))) unsigned int*)g,
        (__attribute__((address_space(3))) unsigned int*)l, 16, 0, 0);
}

// max-reduce across the 16 lanes of a DPP row, pure VALU (no LDS traffic)
static __device__ __forceinline__ float rowmax16(float x) {
    int xi = __builtin_bit_cast(int, x);
    x = fmaxf(x, __builtin_bit_cast(float, __builtin_amdgcn_update_dpp(xi, xi, 0x128, 0xf, 0xf, true))); // row_ror:8
    xi = __builtin_bit_cast(int, x);
    x = fmaxf(x, __builtin_bit_cast(float, __builtin_amdgcn_update_dpp(xi, xi, 0x124, 0xf, 0xf, true))); // row_ror:4
    xi = __builtin_bit_cast(int, x);
    x = fmaxf(x, __builtin_bit_cast(float, __builtin_amdgcn_update_dpp(xi, xi, 0x122, 0xf, 0xf, true))); // row_ror:2
    xi = __builtin_bit_cast(int, x);
    x = fmaxf(x, __builtin_bit_cast(float, __builtin_amdgcn_update_dpp(xi, xi, 0x121, 0xf, 0xf, true))); // row_ror:1
    return x;
}

// ---------------- GroupNorm partial sums: coalesced, 256 blocks, fp32 atomics ----------------
__global__ __launch_bounds__(256) void gn_partial_kernel(const float* __restrict__ x,
                                                         float* __restrict__ statsraw) {
    int blk = blockIdx.x;                 // 0..255
    int t = threadIdx.x;
    size_t row0 = (size_t)blk * 64;       // within B*L rows
    int qd = t & 127;                     // column-quad: channels qd*4..qd*4+3 (one group)
    int rh = t >> 7;                      // 0/1
    const float* base = x + row0 * 512 + qd * 4;
    float s1 = 0.f, s2 = 0.f;
    #pragma unroll 4
    for (int i = 0; i < 32; ++i) {
        int r = rh + i * 2;
        float4 v = *reinterpret_cast<const float4*>(base + (size_t)r * 512);
        s1 += v.x + v.y + v.z + v.w;
        s2 += v.x * v.x + v.y * v.y + v.z * v.z + v.w * v.w;
    }
    __shared__ float a1[256], a2[256];
    a1[t] = s1; a2[t] = s2;
    __syncthreads();
    if (t < 32) {                          // one thread per group
        float u1 = 0.f, u2 = 0.f;
        #pragma unroll
        for (int e = 0; e < 4; ++e) {
            u1 += a1[t * 4 + e] + a1[128 + t * 4 + e];
            u2 += a2[t * 4 + e] + a2[128 + t * 4 + e];
        }
        int b = (int)(row0 >> 12);         // 4096 rows per batch
        atomicAdd(&statsraw[(b * 32 + t) * 2],     u1);
        atomicAdd(&statsraw[(b * 32 + t) * 2 + 1], u2);
    }
}

// ---------------- GroupNorm apply: fp32 -> bf16 xn (finalize stats inline) ----------------
__global__ __launch_bounds__(256) void gn_apply_kernel(const float* __restrict__ x,
                                                       const float* __restrict__ statsraw,
                                                       const float* __restrict__ gsc,
                                                       const float* __restrict__ gbs,
                                                       short* __restrict__ xn) {
    int i4 = blockIdx.x * 256 + threadIdx.x;  // 4 elems each
    int base = i4 * 4;
    int b = base >> 21;                        // / (SEQ*CH)
    int c = base & 511;
    int sidx = (b * 32 + (c >> 4)) * 2;
    float s1 = statsraw[sidx], s2 = statsraw[sidx + 1];
    float mean = s1 * (1.f / 65536.f);
    float var  = s2 * (1.f / 65536.f) - mean * mean;
    float rstd = rsqrtf(var + GEPS);
    float4 xv = reinterpret_cast<const float4*>(x)[i4];
    float4 sv = *reinterpret_cast<const float4*>(gsc + c);
    float4 bv = *reinterpret_cast<const float4*>(gbs + c);
    union { short s[4]; uint2 u; } p;
    p.s[0] = bf16b((xv.x - mean) * rstd * sv.x + bv.x);
    p.s[1] = bf16b((xv.y - mean) * rstd * sv.y + bv.y);
    p.s[2] = bf16b((xv.z - mean) * rstd * sv.z + bv.z);
    p.s[3] = bf16b((xv.w - mean) * rstd * sv.w + bv.w);
    reinterpret_cast<uint2*>(xn)[i4] = p.u;
}

// ---------------- weight transpose: w[K][N] fp32 -> wT[N][K] bf16 (4 weights) ----------------
__global__ __launch_bounds__(256) void wtrans_kernel(const float* __restrict__ w0,
                                                     const float* __restrict__ w1,
                                                     const float* __restrict__ w2,
                                                     const float* __restrict__ w3,
                                                     short* __restrict__ wT) {
    const float* w = (blockIdx.z == 0) ? w0 : (blockIdx.z == 1) ? w1
                   : (blockIdx.z == 2) ? w2 : w3;
    short* out = wT + (size_t)blockIdx.z * CH * CH;
    int n0 = blockIdx.x * 32, k0 = blockIdx.y * 32;
    int tx = threadIdx.x, ty = threadIdx.y;     // (32, 8)
    __shared__ float s[32][33];
    #pragma unroll
    for (int i = 0; i < 4; ++i) {
        int kk = ty + i * 8;
        s[kk][tx] = w[(size_t)(k0 + kk) * CH + n0 + tx];
    }
    __syncthreads();
    #pragma unroll
    for (int i = 0; i < 4; ++i) {
        int nn = ty + i * 8;
        out[(size_t)(n0 + nn) * CH + k0 + tx] = bf16b(s[tx][nn]);
    }
}

// ---------------- v transpose: v[b][l][d] bf16 -> vT[b][d][l] bf16 ----------------
__global__ __launch_bounds__(256) void vtrans_kernel(const short* __restrict__ v,
                                                     short* __restrict__ vT) {
    int b = blockIdx.z;
    int l0 = blockIdx.x * 32, d0 = blockIdx.y * 32;
    int tx = threadIdx.x, ty = threadIdx.y;     // (32, 8)
    __shared__ short s[32][33];
    #pragma unroll
    for (int i = 0; i < 4; ++i) {
        int ll = ty + i * 8;
        s[ll][tx] = v[((size_t)b * SEQ + l0 + ll) * CH + d0 + tx];
    }
    __syncthreads();
    #pragma unroll
    for (int i = 0; i < 4; ++i) {
        int dd = ty + i * 8;
        vT[((size_t)b * CH + d0 + dd) * SEQ + l0 + tx] = s[tx][dd];
    }
}

// ---------------- GEMM: C[m][n] = sum_k A[m][k]*BT[n][k] + bias[n]  (M=16384,N=512,K=512)
__global__ __launch_bounds__(256) void gemm_bt_kernel(const short* __restrict__ A,
                                                      const short* __restrict__ BT,
                                                      const float* __restrict__ bias,
                                                      short* __restrict__ outb,
                                                      float* __restrict__ outf,
                                                      const float* __restrict__ resid) {
    __shared__ short As[128 * 64];
    __shared__ short Bs[128 * 64];
    int m0 = blockIdx.x * 128, n0 = blockIdx.y * 128;
    int t = threadIdx.x;
    int w = t >> 6, lane = t & 63;
    int wr = w >> 1, wc = w & 1;
    int l15 = lane & 15, l4 = lane >> 4;
    floatx4 acc[4][4];
    #pragma unroll
    for (int i = 0; i < 4; ++i)
        #pragma unroll
        for (int j = 0; j < 4; ++j) acc[i][j] = (floatx4){0.f, 0.f, 0.f, 0.f};

    for (int k0 = 0; k0 < 512; k0 += 64) {
        __syncthreads();
        #pragma unroll
        for (int i = 0; i < 4; ++i) {
            int c = i * 256 + t;
            int row = c >> 3, j = (c & 7) ^ (row & 7);   // inverse swizzle on source
            dma16(&A[(size_t)(m0 + row) * 512 + k0 + j * 8], &As[(c & ~63) * 8]);
            dma16(&BT[(size_t)(n0 + row) * 512 + k0 + j * 8], &Bs[(c & ~63) * 8]);
        }
        __syncthreads();   // drains vmcnt(0) -> tiles ready
        #pragma unroll
        for (int kk = 0; kk < 64; kk += 32) {
            short8 af[4], bf[4];
            #pragma unroll
            for (int i = 0; i < 4; ++i) {
                int row = wr * 64 + i * 16 + l15;
                int j = (kk >> 3) + l4;
                af[i] = *reinterpret_cast<const short8*>(&As[(row * 8 + (j ^ (l15 & 7))) * 8]);
            }
            #pragma unroll
            for (int j2 = 0; j2 < 4; ++j2) {
                int row = wc * 64 + j2 * 16 + l15;
                int j = (kk >> 3) + l4;
                bf[j2] = *reinterpret_cast<const short8*>(&Bs[(row * 8 + (j ^ (l15 & 7))) * 8]);
            }
            #pragma unroll
            for (int i = 0; i < 4; ++i)
                #pragma unroll
                for (int j2 = 0; j2 < 4; ++j2)
                    acc[i][j2] = __builtin_amdgcn_mfma_f32_16x16x32_bf16(af[i], bf[j2], acc[i][j2], 0, 0, 0);
        }
    }
    #pragma unroll
    for (int i = 0; i < 4; ++i) {
        #pragma unroll
        for (int j = 0; j < 4; ++j) {
            #pragma unroll
            for (int r = 0; r < 4; ++r) {
                int row = m0 + wr * 64 + i * 16 + l4 * 4 + r;
                int col = n0 + wc * 64 + j * 16 + l15;
                float vv = acc[i][j][r] + bias[col];
                if (outf) outf[(size_t)row * 512 + col] = vv + resid[(size_t)row * 512 + col];
                else      outb[(size_t)row * 512 + col] = bf16b(vv);
            }
        }
    }
}

// ---------------- flash attention (split-s, split-d PV, DMA staging) --------
// Per block: 64 q-rows, sweep half of s. QK: wave w computes S for q-rows [w*16,w*16+16).
// PV: wave w computes O[all 64 q][d-slice w*128..w*128+128) -> V B-frags reused 4x.
// LDS: K[0,16384) V[16384,32768) P[32768,34816) alpha f32 @ short-idx 34816 (64 floats).
__global__ __launch_bounds__(256, 2) void flash_kernel(const short* __restrict__ q,
                                                       const short* __restrict__ k,
                                                       const short* __restrict__ vT,
                                                       short* __restrict__ Opart,
                                                       float* __restrict__ ml) {
    __shared__ short smem[34944];   // 69,888 B -> 2 blocks/CU
    float* alds = (float*)(smem + 34816);
    int b = blockIdx.z;
    int part = blockIdx.y;
    int q0 = blockIdx.x * 64;
    int t = threadIdx.x, w = t >> 6, lane = t & 63;
    int l15 = lane & 15, l4 = lane >> 4;
    const float scale = 0.044194173824159216f;  // 1/sqrt(512)

    // Q fragments in registers: rows w*16 + l15, all 512 k
    short8 qf[16];
    {
        const short* qrow = q + ((size_t)b * SEQ + q0 + w * 16 + l15) * 512;
        #pragma unroll
        for (int ks = 0; ks < 16; ++ks)
            qf[ks] = *reinterpret_cast<const short8*>(qrow + ks * 32 + l4 * 8);
    }

    // O accumulator: acc[g][dt] = C-tile for q-sub g (rows g*16..), d-tile w*128+dt*16
    floatx4 acc[4][8];
    #pragma unroll
    for (int g = 0; g < 4; ++g)
        #pragma unroll
        for (int dt = 0; dt < 8; ++dt) acc[g][dt] = (floatx4){0.f, 0.f, 0.f, 0.f};
    floatx4 lacc = (floatx4){0.f, 0.f, 0.f, 0.f};   // row sums (own 16 rows) via MFMA-ones
    float mprev[4] = {-1e30f, -1e30f, -1e30f, -1e30f};

    short8 ones;
    #pragma unroll
    for (int j = 0; j < 8; ++j) ones[j] = (short)0x3F80;   // bf16 1.0

    const short* kbase = k  + (size_t)b * SEQ * 512;
    const short* vbase = vT + (size_t)b * 512 * SEQ;

    const int vswz = l4 ^ ((l15 >> 1) & 3);    // V read swizzle (d-tile-independent)
    const int kswz = l15 & 7;                  // K read swizzle mask
    const int s_begin = part * (SEQ / 2);
    const int s_end   = s_begin + (SEQ / 2);

    for (int s0 = s_begin; s0 < s_end; s0 += 32) {
        __syncthreads();                                   // (A) prev iter LDS reads done
        {   // DMA K tile
            const short* ksrc = kbase + (size_t)s0 * 512;
            #pragma unroll
            for (int i = 0; i < 8; ++i) {
                int c = i * 256 + t;
                int row = c >> 6, j = (c & 63) ^ (row & 7);
                dma16(ksrc + row * 512 + j * 8, &smem[(c & ~63) * 8]);
            }
        }
        {   // DMA Vt tile
            #pragma unroll
            for (int i = 0; i < 8; ++i) {
                int c = i * 256 + t;
                int d = c >> 2, jv = (c & 3) ^ ((d >> 1) & 3);
                dma16(vbase + (size_t)d * SEQ + s0 + jv * 8, &smem[16384 + (c & ~63) * 8]);
            }
        }
        __syncthreads();                                   // (B) vmcnt drain: tiles ready

        // --- QK^T for own 16 rows: S[16][32] in two 16x16 C-tiles
        floatx4 sa0 = (floatx4){0.f, 0.f, 0.f, 0.f};
        floatx4 sa1 = (floatx4){0.f, 0.f, 0.f, 0.f};
        #pragma unroll
        for (int ks = 0; ks < 16; ++ks) {
            int js = (ks * 4 + l4) ^ kswz;
            short8 b0 = *reinterpret_cast<const short8*>(&smem[(l15 * 64 + js) * 8]);
            short8 b1 = *reinterpret_cast<const short8*>(&smem[((l15 + 16) * 64 + js) * 8]);
            sa0 = __builtin_amdgcn_mfma_f32_16x16x32_bf16(qf[ks], b0, sa0, 0, 0, 0);
            sa1 = __builtin_amdgcn_mfma_f32_16x16x32_bf16(qf[ks], b1, sa1, 0, 0, 0);
        }

        // --- online softmax for own rows (row = l4*4+r)
        float p0[4], p1[4], alpha[4];
        bool changed = false;
        #pragma unroll
        for (int r = 0; r < 4; ++r) {
            float v0 = sa0[r] * scale, v1 = sa1[r] * scale;
            float mx = rowmax16(fmaxf(v0, v1));
            float nm = fmaxf(mprev[r], mx);
            alpha[r] = __expf(mprev[r] - nm);
            changed |= (nm > mprev[r]);
            p0[r] = __expf(v0 - nm);
            p1[r] = __expf(v1 - nm);
            mprev[r] = nm;
        }
        if (__ballot(changed)) {
            #pragma unroll
            for (int r = 0; r < 4; ++r) lacc[r] *= alpha[r];
        }

        // write P (own rows) + alpha to dedicated region (no K alias -> no barrier needed here)
        short* Ps = smem + 32768 + w * 512;
        #pragma unroll
        for (int r = 0; r < 4; ++r) {
            Ps[(l4 * 4 + r) * 32 + l15]      = bf16b(p0[r]);
            Ps[(l4 * 4 + r) * 32 + 16 + l15] = bf16b(p1[r]);
        }
        if (l15 == 0) {
            #pragma unroll
            for (int r = 0; r < 4; ++r) alds[w * 16 + l4 * 4 + r] = alpha[r];
        }
        __syncthreads();                                   // (C) P + alpha visible to all waves

        // --- rescale O by per-row alphas (broadcast LDS reads)
        #pragma unroll
        for (int g = 0; g < 4; ++g) {
            float avg[4];
            #pragma unroll
            for (int r = 0; r < 4; ++r) avg[r] = alds[g * 16 + l4 * 4 + r];
            bool any = (avg[0] != 1.f) | (avg[1] != 1.f) | (avg[2] != 1.f) | (avg[3] != 1.f);
            if (__ballot(any)) {
                #pragma unroll
                for (int dt = 0; dt < 8; ++dt)
                    #pragma unroll
                    for (int r = 0; r < 4; ++r) acc[g][dt][r] *= avg[r];
            }
        }

        // --- row sums for own rows: MFMA with ones
        {
            short8 pw = *reinterpret_cast<const short8*>(smem + 32768 + w * 512 + l15 * 32 + l4 * 8);
            lacc = __builtin_amdgcn_mfma_f32_16x16x32_bf16(pw, ones, lacc, 0, 0, 0);
        }

        // --- PV split-d: A = P[g][16][32] (all 4 subtiles), B = Vt d-slice w*128..+128
        short8 pf[4];
        #pragma unroll
        for (int g = 0; g < 4; ++g)
            pf[g] = *reinterpret_cast<const short8*>(smem + 32768 + g * 512 + l15 * 32 + l4 * 8);
        #pragma unroll
        for (int dt = 0; dt < 8; ++dt) {
            int d = w * 128 + dt * 16 + l15;
            short8 vf = *reinterpret_cast<const short8*>(&smem[16384 + (d * 4 + vswz) * 8]);
            #pragma unroll
            for (int g = 0; g < 4; ++g)
                acc[g][dt] = __builtin_amdgcn_mfma_f32_16x16x32_bf16(pf[g], vf, acc[g][dt], 0, 0, 0);
        }
    }

    // epilogue: store UNNORMALIZED partial O (bf16): row q0+g*16+l4*4+r, col w*128+dt*16+l15
    short* obase = Opart + (((size_t)part * BATCH + b) * SEQ + q0) * 512;
    #pragma unroll
    for (int g = 0; g < 4; ++g)
        #pragma unroll
        for (int r = 0; r < 4; ++r)
            #pragma unroll
            for (int dt = 0; dt < 8; ++dt)
                obase[(size_t)(g * 16 + l4 * 4 + r) * 512 + w * 128 + dt * 16 + l15] = bf16b(acc[g][dt][r]);
    if (l15 == 0) {
        #pragma unroll
        for (int r = 0; r < 4; ++r) {
            size_t rowg = ((size_t)part * BATCH + b) * SEQ + q0 + w * 16 + l4 * 4 + r;
            ml[rowg * 2]     = mprev[r];
            ml[rowg * 2 + 1] = lacc[r];
        }
    }
}

// ---------------- combine the two s-partials -> normalized attn bf16 ----------------
__global__ __launch_bounds__(256) void combine_kernel(const short* __restrict__ Opart,
                                                      const float* __restrict__ ml,
                                                      short* __restrict__ attn) {
    int i8 = blockIdx.x * 256 + threadIdx.x;       // 8 bf16 per thread
    size_t row = (size_t)i8 >> 6;                  // b*SEQ + l
    float m0 = ml[row * 2], l0 = ml[row * 2 + 1];
    float m1 = ml[((size_t)BATCH * SEQ + row) * 2], l1 = ml[((size_t)BATCH * SEQ + row) * 2 + 1];
    float m = fmaxf(m0, m1);
    float e0 = __expf(m0 - m), e1 = __expf(m1 - m);
    float inv = 1.f / (e0 * l0 + e1 * l1);
    e0 *= inv; e1 *= inv;
    union { uint4 u; short s[8]; } a, bb, o;
    a.u  = reinterpret_cast<const uint4*>(Opart)[i8];
    bb.u = reinterpret_cast<const uint4*>(Opart)[(size_t)BATCH * SEQ * 512 / 8 + i8];
    #pragma unroll
    for (int e = 0; e < 8; ++e)
        o.s[e] = bf16b(bf2f(a.s[e]) * e0 + bf2f(bb.s[e]) * e1);
    reinterpret_cast<uint4*>(attn)[i8] = o.u;
}

extern "C" void kernel_launch(void* const* d_in, const int* in_sizes, int n_in,
                              void* d_out, int out_size, void* d_ws, size_t ws_size,
                              hipStream_t stream) {
    const float* x   = (const float*)d_in[0];
    const float* gsc = (const float*)d_in[1];
    const float* gbs = (const float*)d_in[2];
    const float* wq  = (const float*)d_in[3];
    const float* bq  = (const float*)d_in[4];
    const float* wk  = (const float*)d_in[5];
    const float* bk  = (const float*)d_in[6];
    const float* wv  = (const float*)d_in[7];
    const float* bv  = (const float*)d_in[8];
    const float* wo  = (const float*)d_in[9];
    const float* bo  = (const float*)d_in[10];
    float* out = (float*)d_out;

    char* ws = (char*)d_ws;
    const size_t MB = 1ull << 20;
    short* xn    = (short*)ws;                    // 16MB; reused as attn (combine output)
    short* qb    = (short*)(ws + 16 * MB);
    short* kb    = (short*)(ws + 32 * MB);
    short* vTb   = (short*)(ws + 48 * MB);
    short* wT    = (short*)(ws + 64 * MB);        // 2MB: 4 x [512][512] bf16
    float* stats = (float*)(ws + 66 * MB);        // raw sums, 256 floats
    float* ml    = (float*)(ws + 66 * MB + 65536);// 256KB
    short* vb    = (short*)(ws + 67 * MB);        // 16MB, dead after vtrans
    short* Opart = (short*)(ws + 67 * MB);        // 32MB, overlaps vb (vb dead by then)
    short* attn  = xn;

    hipMemsetAsync(stats, 0, 256 * sizeof(float), stream);
    gn_partial_kernel<<<256, 256, 0, stream>>>(x, stats);
    gn_apply_kernel<<<8192, 256, 0, stream>>>(x, stats, gsc, gbs, xn);
    wtrans_kernel<<<dim3(16, 16, 4), dim3(32, 8), 0, stream>>>(wq, wk, wv, wo, wT);

    short* wqT = wT;
    short* wkT = wT + 262144;
    short* wvT = wT + 524288;
    short* woT = wT + 786432;

    gemm_bt_kernel<<<dim3(128, 4), 256, 0, stream>>>(xn, wqT, bq, qb, nullptr, nullptr);
    gemm_bt_kernel<<<dim3(128, 4), 256, 0, stream>>>(xn, wkT, bk, kb, nullptr, nullptr);
    gemm_bt_kernel<<<dim3(128, 4), 256, 0, stream>>>(xn, wvT, bv, vb, nullptr, nullptr);
    vtrans_kernel<<<dim3(128, 16, 4), dim3(32, 8), 0, stream>>>(vb, vTb);
    flash_kernel<<<dim3(64, 2, 4), 256, 0, stream>>>(qb, kb, vTb, Opart, ml);
    combine_kernel<<<4096, 256, 0, stream>>>(Opart, ml, attn);
    gemm_bt_kernel<<<dim3(128, 4), 256, 0, stream>>>(attn, woT, bo, nullptr, out, x);
}

// Round 5
// 539.156 us; speedup vs baseline: 1.1041x; 1.1041x over previous
//
#include <hip/hip_runtime.h>
#include <hip/hip_bf16.h>
#include <stdint.h>

#define BATCH 4
#define SEQ   4096          // 64*64 spatial
#define CH    512
#define NGRP  32
#define GEPS  1e-6f

typedef short  short8  __attribute__((ext_vector_type(8)));
typedef float  floatx4 __attribute__((ext_vector_type(4)));

static __device__ __forceinline__ short bf16b(float f) {
    __hip_bfloat16 h = __float2bfloat16(f);
    return __builtin_bit_cast(short, h);
}
static __device__ __forceinline__ float bf2f(short s) {
    unsigned u = ((unsigned)(unsigned short)s) << 16;
    return __builtin_bit_cast(float, u);
}

// async global->LDS, 16B per lane. LDS dest = wave-uniform base + lane*16.
static __device__ __forceinline__ void dma16(const void* g, void* l) {
    __builtin_amdgcn_global_load_lds(
        (const __attribute__((address_space(1))) unsigned int*)g,
        (__attribute__((address_space(3))) unsigned int*)l, 16, 0, 0);
}

// max-reduce across the 16 lanes of a DPP row, pure VALU (no LDS traffic)
static __device__ __forceinline__ float rowmax16(float x) {
    int xi = __builtin_bit_cast(int, x);
    x = fmaxf(x, __builtin_bit_cast(float, __builtin_amdgcn_update_dpp(xi, xi, 0x128, 0xf, 0xf, true))); // row_ror:8
    xi = __builtin_bit_cast(int, x);
    x = fmaxf(x, __builtin_bit_cast(float, __builtin_amdgcn_update_dpp(xi, xi, 0x124, 0xf, 0xf, true))); // row_ror:4
    xi = __builtin_bit_cast(int, x);
    x = fmaxf(x, __builtin_bit_cast(float, __builtin_amdgcn_update_dpp(xi, xi, 0x122, 0xf, 0xf, true))); // row_ror:2
    xi = __builtin_bit_cast(int, x);
    x = fmaxf(x, __builtin_bit_cast(float, __builtin_amdgcn_update_dpp(xi, xi, 0x121, 0xf, 0xf, true))); // row_ror:1
    return x;
}

// ---------------- GroupNorm partial sums ----------------
__global__ __launch_bounds__(256) void gn_partial_kernel(const float* __restrict__ x,
                                                         float* __restrict__ statsraw) {
    int blk = blockIdx.x;                 // 0..255
    int t = threadIdx.x;
    size_t row0 = (size_t)blk * 64;
    int qd = t & 127;
    int rh = t >> 7;
    const float* base = x + row0 * 512 + qd * 4;
    float s1 = 0.f, s2 = 0.f;
    #pragma unroll 4
    for (int i = 0; i < 32; ++i) {
        int r = rh + i * 2;
        float4 v = *reinterpret_cast<const float4*>(base + (size_t)r * 512);
        s1 += v.x + v.y + v.z + v.w;
        s2 += v.x * v.x + v.y * v.y + v.z * v.z + v.w * v.w;
    }
    __shared__ float a1[256], a2[256];
    a1[t] = s1; a2[t] = s2;
    __syncthreads();
    if (t < 32) {
        float u1 = 0.f, u2 = 0.f;
        #pragma unroll
        for (int e = 0; e < 4; ++e) {
            u1 += a1[t * 4 + e] + a1[128 + t * 4 + e];
            u2 += a2[t * 4 + e] + a2[128 + t * 4 + e];
        }
        int b = (int)(row0 >> 12);
        atomicAdd(&statsraw[(b * 32 + t) * 2],     u1);
        atomicAdd(&statsraw[(b * 32 + t) * 2 + 1], u2);
    }
}

// ---------------- GroupNorm apply ----------------
__global__ __launch_bounds__(256) void gn_apply_kernel(const float* __restrict__ x,
                                                       const float* __restrict__ statsraw,
                                                       const float* __restrict__ gsc,
                                                       const float* __restrict__ gbs,
                                                       short* __restrict__ xn) {
    int i4 = blockIdx.x * 256 + threadIdx.x;
    int base = i4 * 4;
    int b = base >> 21;
    int c = base & 511;
    int sidx = (b * 32 + (c >> 4)) * 2;
    float s1 = statsraw[sidx], s2 = statsraw[sidx + 1];
    float mean = s1 * (1.f / 65536.f);
    float var  = s2 * (1.f / 65536.f) - mean * mean;
    float rstd = rsqrtf(var + GEPS);
    float4 xv = reinterpret_cast<const float4*>(x)[i4];
    float4 sv = *reinterpret_cast<const float4*>(gsc + c);
    float4 bv = *reinterpret_cast<const float4*>(gbs + c);
    union { short s[4]; uint2 u; } p;
    p.s[0] = bf16b((xv.x - mean) * rstd * sv.x + bv.x);
    p.s[1] = bf16b((xv.y - mean) * rstd * sv.y + bv.y);
    p.s[2] = bf16b((xv.z - mean) * rstd * sv.z + bv.z);
    p.s[3] = bf16b((xv.w - mean) * rstd * sv.w + bv.w);
    reinterpret_cast<uint2*>(xn)[i4] = p.u;
}

// ---------------- weight transpose ----------------
__global__ __launch_bounds__(256) void wtrans_kernel(const float* __restrict__ w0,
                                                     const float* __restrict__ w1,
                                                     const float* __restrict__ w2,
                                                     const float* __restrict__ w3,
                                                     short* __restrict__ wT) {
    const float* w = (blockIdx.z == 0) ? w0 : (blockIdx.z == 1) ? w1
                   : (blockIdx.z == 2) ? w2 : w3;
    short* out = wT + (size_t)blockIdx.z * CH * CH;
    int n0 = blockIdx.x * 32, k0 = blockIdx.y * 32;
    int tx = threadIdx.x, ty = threadIdx.y;
    __shared__ float s[32][33];
    #pragma unroll
    for (int i = 0; i < 4; ++i) {
        int kk = ty + i * 8;
        s[kk][tx] = w[(size_t)(k0 + kk) * CH + n0 + tx];
    }
    __syncthreads();
    #pragma unroll
    for (int i = 0; i < 4; ++i) {
        int nn = ty + i * 8;
        out[(size_t)(n0 + nn) * CH + k0 + tx] = bf16b(s[tx][nn]);
    }
}

// ---------------- v transpose ----------------
__global__ __launch_bounds__(256) void vtrans_kernel(const short* __restrict__ v,
                                                     short* __restrict__ vT) {
    int b = blockIdx.z;
    int l0 = blockIdx.x * 32, d0 = blockIdx.y * 32;
    int tx = threadIdx.x, ty = threadIdx.y;
    __shared__ short s[32][33];
    #pragma unroll
    for (int i = 0; i < 4; ++i) {
        int ll = ty + i * 8;
        s[ll][tx] = v[((size_t)b * SEQ + l0 + ll) * CH + d0 + tx];
    }
    __syncthreads();
    #pragma unroll
    for (int i = 0; i < 4; ++i) {
        int dd = ty + i * 8;
        vT[((size_t)b * CH + d0 + dd) * SEQ + l0 + tx] = s[tx][dd];
    }
}

// ---------------- fused QKV GEMM ----------------
__global__ __launch_bounds__(256) void gemm_qkv_kernel(const short* __restrict__ A,
                                                       const short* __restrict__ wT,
                                                       const float* __restrict__ bq,
                                                       const float* __restrict__ bk,
                                                       const float* __restrict__ bv,
                                                       short* __restrict__ outbase) {
    __shared__ short As[128 * 64];
    __shared__ short Bs[128 * 64];
    int m0 = blockIdx.x * 128;
    int nblk = blockIdx.y;                  // 0..11
    int which = nblk >> 2;                  // 0=q,1=k,2=v (block-uniform)
    int n0 = (nblk & 3) * 128;
    const short* BT = wT + (size_t)which * 512 * 512;
    const float* bias = (which == 0) ? bq : (which == 1) ? bk : bv;
    short* outb = outbase + (size_t)which * BATCH * SEQ * 512;
    int t = threadIdx.x;
    int w = t >> 6, lane = t & 63;
    int wr = w >> 1, wc = w & 1;
    int l15 = lane & 15, l4 = lane >> 4;
    floatx4 acc[4][4];
    #pragma unroll
    for (int i = 0; i < 4; ++i)
        #pragma unroll
        for (int j = 0; j < 4; ++j) acc[i][j] = (floatx4){0.f, 0.f, 0.f, 0.f};

    for (int k0 = 0; k0 < 512; k0 += 64) {
        __syncthreads();
        #pragma unroll
        for (int i = 0; i < 4; ++i) {
            int c = i * 256 + t;
            int row = c >> 3, j = (c & 7) ^ (row & 7);
            dma16(&A[(size_t)(m0 + row) * 512 + k0 + j * 8], &As[(c & ~63) * 8]);
            dma16(&BT[(size_t)(n0 + row) * 512 + k0 + j * 8], &Bs[(c & ~63) * 8]);
        }
        __syncthreads();
        #pragma unroll
        for (int kk = 0; kk < 64; kk += 32) {
            short8 af[4], bf[4];
            #pragma unroll
            for (int i = 0; i < 4; ++i) {
                int row = wr * 64 + i * 16 + l15;
                int j = (kk >> 3) + l4;
                af[i] = *reinterpret_cast<const short8*>(&As[(row * 8 + (j ^ (l15 & 7))) * 8]);
            }
            #pragma unroll
            for (int j2 = 0; j2 < 4; ++j2) {
                int row = wc * 64 + j2 * 16 + l15;
                int j = (kk >> 3) + l4;
                bf[j2] = *reinterpret_cast<const short8*>(&Bs[(row * 8 + (j ^ (l15 & 7))) * 8]);
            }
            #pragma unroll
            for (int i = 0; i < 4; ++i)
                #pragma unroll
                for (int j2 = 0; j2 < 4; ++j2)
                    acc[i][j2] = __builtin_amdgcn_mfma_f32_16x16x32_bf16(af[i], bf[j2], acc[i][j2], 0, 0, 0);
        }
    }
    #pragma unroll
    for (int i = 0; i < 4; ++i)
        #pragma unroll
        for (int j = 0; j < 4; ++j)
            #pragma unroll
            for (int r = 0; r < 4; ++r) {
                int row = m0 + wr * 64 + i * 16 + l4 * 4 + r;
                int col = n0 + wc * 64 + j * 16 + l15;
                outb[(size_t)row * 512 + col] = bf16b(acc[i][j][r] + bias[col]);
            }
}

// ---------------- output GEMM: bias + residual, fp32 out ----------------
__global__ __launch_bounds__(256) void gemm_bt_kernel(const short* __restrict__ A,
                                                      const short* __restrict__ BT,
                                                      const float* __restrict__ bias,
                                                      float* __restrict__ outf,
                                                      const float* __restrict__ resid) {
    __shared__ short As[128 * 64];
    __shared__ short Bs[128 * 64];
    int m0 = blockIdx.x * 128, n0 = blockIdx.y * 128;
    int t = threadIdx.x;
    int w = t >> 6, lane = t & 63;
    int wr = w >> 1, wc = w & 1;
    int l15 = lane & 15, l4 = lane >> 4;
    floatx4 acc[4][4];
    #pragma unroll
    for (int i = 0; i < 4; ++i)
        #pragma unroll
        for (int j = 0; j < 4; ++j) acc[i][j] = (floatx4){0.f, 0.f, 0.f, 0.f};

    for (int k0 = 0; k0 < 512; k0 += 64) {
        __syncthreads();
        #pragma unroll
        for (int i = 0; i < 4; ++i) {
            int c = i * 256 + t;
            int row = c >> 3, j = (c & 7) ^ (row & 7);
            dma16(&A[(size_t)(m0 + row) * 512 + k0 + j * 8], &As[(c & ~63) * 8]);
            dma16(&BT[(size_t)(n0 + row) * 512 + k0 + j * 8], &Bs[(c & ~63) * 8]);
        }
        __syncthreads();
        #pragma unroll
        for (int kk = 0; kk < 64; kk += 32) {
            short8 af[4], bf[4];
            #pragma unroll
            for (int i = 0; i < 4; ++i) {
                int row = wr * 64 + i * 16 + l15;
                int j = (kk >> 3) + l4;
                af[i] = *reinterpret_cast<const short8*>(&As[(row * 8 + (j ^ (l15 & 7))) * 8]);
            }
            #pragma unroll
            for (int j2 = 0; j2 < 4; ++j2) {
                int row = wc * 64 + j2 * 16 + l15;
                int j = (kk >> 3) + l4;
                bf[j2] = *reinterpret_cast<const short8*>(&Bs[(row * 8 + (j ^ (l15 & 7))) * 8]);
            }
            #pragma unroll
            for (int i = 0; i < 4; ++i)
                #pragma unroll
                for (int j2 = 0; j2 < 4; ++j2)
                    acc[i][j2] = __builtin_amdgcn_mfma_f32_16x16x32_bf16(af[i], bf[j2], acc[i][j2], 0, 0, 0);
        }
    }
    #pragma unroll
    for (int i = 0; i < 4; ++i)
        #pragma unroll
        for (int j = 0; j < 4; ++j)
            #pragma unroll
            for (int r = 0; r < 4; ++r) {
                int row = m0 + wr * 64 + i * 16 + l4 * 4 + r;
                int col = n0 + wc * 64 + j * 16 + l15;
                float vv = acc[i][j][r] + bias[col];
                outf[(size_t)row * 512 + col] = vv + resid[(size_t)row * 512 + col];
            }
}

// ---------------- flash attention (r3 structure + 2 blocks/CU) --------
__global__ __launch_bounds__(256, 2) void flash_kernel(const short* __restrict__ q,
                                                       const short* __restrict__ k,
                                                       const short* __restrict__ vT,
                                                       short* __restrict__ Opart,
                                                       float* __restrict__ ml) {
    __shared__ short smem[32768];   // 64 KB -> 2 blocks/CU
    int b = blockIdx.z;
    int part = blockIdx.y;
    int q0 = blockIdx.x * 64;
    int t = threadIdx.x, w = t >> 6, lane = t & 63;
    int l15 = lane & 15, l4 = lane >> 4;
    const float scale = 0.044194173824159216f;  // 1/sqrt(512)

    short8 qf[16];
    {
        const short* qrow = q + ((size_t)b * SEQ + q0 + w * 16 + l15) * 512;
        #pragma unroll
        for (int ks = 0; ks < 16; ++ks)
            qf[ks] = *reinterpret_cast<const short8*>(qrow + ks * 32 + l4 * 8);
    }

    floatx4 acc[32];
    #pragma unroll
    for (int i = 0; i < 32; ++i) acc[i] = (floatx4){0.f, 0.f, 0.f, 0.f};
    floatx4 lacc = (floatx4){0.f, 0.f, 0.f, 0.f};
    float mprev[4] = {-1e30f, -1e30f, -1e30f, -1e30f};

    short8 ones;
    #pragma unroll
    for (int j = 0; j < 8; ++j) ones[j] = (short)0x3F80;   // bf16 1.0

    const short* kbase = k  + (size_t)b * SEQ * 512;
    const short* vbase = vT + (size_t)b * 512 * SEQ;

    const int vswz = l4 ^ ((l15 >> 1) & 3);
    const int kswz = l15 & 7;
    const int s_begin = part * (SEQ / 2);
    const int s_end   = s_begin + (SEQ / 2);

    for (int s0 = s_begin; s0 < s_end; s0 += 32) {
        __syncthreads();                                   // (a) prev iter LDS reads done
        {
            const short* ksrc = kbase + (size_t)s0 * 512;
            #pragma unroll
            for (int i = 0; i < 8; ++i) {
                int c = i * 256 + t;
                int row = c >> 6, j = (c & 63) ^ (row & 7);
                dma16(ksrc + row * 512 + j * 8, &smem[(c & ~63) * 8]);
            }
        }
        {
            #pragma unroll
            for (int i = 0; i < 8; ++i) {
                int c = i * 256 + t;
                int d = c >> 2, jv = (c & 3) ^ ((d >> 1) & 3);
                dma16(vbase + (size_t)d * SEQ + s0 + jv * 8, &smem[16384 + (c & ~63) * 8]);
            }
        }
        __syncthreads();                                   // (c) tiles ready

        floatx4 sa0 = (floatx4){0.f, 0.f, 0.f, 0.f};
        floatx4 sa1 = (floatx4){0.f, 0.f, 0.f, 0.f};
        #pragma unroll
        for (int ks = 0; ks < 16; ++ks) {
            int js = (ks * 4 + l4) ^ kswz;
            short8 b0 = *reinterpret_cast<const short8*>(&smem[(l15 * 64 + js) * 8]);
            short8 b1 = *reinterpret_cast<const short8*>(&smem[((l15 + 16) * 64 + js) * 8]);
            sa0 = __builtin_amdgcn_mfma_f32_16x16x32_bf16(qf[ks], b0, sa0, 0, 0, 0);
            sa1 = __builtin_amdgcn_mfma_f32_16x16x32_bf16(qf[ks], b1, sa1, 0, 0, 0);
        }

        float p0[4], p1[4], alpha[4];
        bool changed = false;
        #pragma unroll
        for (int r = 0; r < 4; ++r) {
            float v0 = sa0[r] * scale, v1 = sa1[r] * scale;
            float mx = rowmax16(fmaxf(v0, v1));
            float nm = fmaxf(mprev[r], mx);
            alpha[r] = __expf(mprev[r] - nm);
            changed |= (nm > mprev[r]);
            p0[r] = __expf(v0 - nm);
            p1[r] = __expf(v1 - nm);
            mprev[r] = nm;
        }
        if (__ballot(changed)) {
            #pragma unroll
            for (int i = 0; i < 32; ++i)
                #pragma unroll
                for (int r = 0; r < 4; ++r) acc[i][r] *= alpha[r];
            #pragma unroll
            for (int r = 0; r < 4; ++r) lacc[r] *= alpha[r];
        }

        __syncthreads();                      // (e) all QK reads of K tile done
        short* Ps = smem + w * 512;
        #pragma unroll
        for (int r = 0; r < 4; ++r) {
            Ps[(l4 * 4 + r) * 32 + l15]      = bf16b(p0[r]);
            Ps[(l4 * 4 + r) * 32 + 16 + l15] = bf16b(p1[r]);
        }

        short8 pf = *reinterpret_cast<const short8*>(Ps + l15 * 32 + l4 * 8);
        lacc = __builtin_amdgcn_mfma_f32_16x16x32_bf16(pf, ones, lacc, 0, 0, 0);
        #pragma unroll
        for (int tt = 0; tt < 32; ++tt) {
            int d = tt * 16 + l15;
            short8 vf = *reinterpret_cast<const short8*>(&smem[16384 + (d * 4 + vswz) * 8]);
            acc[tt] = __builtin_amdgcn_mfma_f32_16x16x32_bf16(pf, vf, acc[tt], 0, 0, 0);
        }
    }

    short* obase = Opart + (((size_t)part * BATCH + b) * SEQ + q0 + w * 16) * 512;
    #pragma unroll
    for (int r = 0; r < 4; ++r) {
        #pragma unroll
        for (int tt = 0; tt < 32; ++tt)
            obase[(size_t)(l4 * 4 + r) * 512 + tt * 16 + l15] = bf16b(acc[tt][r]);
    }
    if (l15 == 0) {
        #pragma unroll
        for (int r = 0; r < 4; ++r) {
            size_t rowg = ((size_t)part * BATCH + b) * SEQ + q0 + w * 16 + l4 * 4 + r;
            ml[rowg * 2]     = mprev[r];
            ml[rowg * 2 + 1] = lacc[r];
        }
    }
}

// ---------------- combine ----------------
__global__ __launch_bounds__(256) void combine_kernel(const short* __restrict__ Opart,
                                                      const float* __restrict__ ml,
                                                      short* __restrict__ attn) {
    int i8 = blockIdx.x * 256 + threadIdx.x;
    size_t row = (size_t)i8 >> 6;
    float m0 = ml[row * 2], l0 = ml[row * 2 + 1];
    float m1 = ml[((size_t)BATCH * SEQ + row) * 2], l1 = ml[((size_t)BATCH * SEQ + row) * 2 + 1];
    float m = fmaxf(m0, m1);
    float e0 = __expf(m0 - m), e1 = __expf(m1 - m);
    float inv = 1.f / (e0 * l0 + e1 * l1);
    e0 *= inv; e1 *= inv;
    union { uint4 u; short s[8]; } a, bb, o;
    a.u  = reinterpret_cast<const uint4*>(Opart)[i8];
    bb.u = reinterpret_cast<const uint4*>(Opart)[(size_t)BATCH * SEQ * 512 / 8 + i8];
    #pragma unroll
    for (int e = 0; e < 8; ++e)
        o.s[e] = bf16b(bf2f(a.s[e]) * e0 + bf2f(bb.s[e]) * e1);
    reinterpret_cast<uint4*>(attn)[i8] = o.u;
}

extern "C" void kernel_launch(void* const* d_in, const int* in_sizes, int n_in,
                              void* d_out, int out_size, void* d_ws, size_t ws_size,
                              hipStream_t stream) {
    const float* x   = (const float*)d_in[0];
    const float* gsc = (const float*)d_in[1];
    const float* gbs = (const float*)d_in[2];
    const float* wq  = (const float*)d_in[3];
    const float* bq  = (const float*)d_in[4];
    const float* wk  = (const float*)d_in[5];
    const float* bk  = (const float*)d_in[6];
    const float* wv  = (const float*)d_in[7];
    const float* bv  = (const float*)d_in[8];
    const float* wo  = (const float*)d_in[9];
    const float* bo  = (const float*)d_in[10];
    float* out = (float*)d_out;

    char* ws = (char*)d_ws;
    const size_t MB = 1ull << 20;
    short* xn    = (short*)ws;                    // 16MB; reused as attn (combine output)
    short* qb    = (short*)(ws + 16 * MB);        // q(16) k(16) v(16) contiguous -> fused GEMM
    short* vraw  = (short*)(ws + 48 * MB);        // raw v (fused GEMM which=2 lands here)
    short* wT    = (short*)(ws + 64 * MB);        // 2MB: 4 x [512][512] bf16
    float* stats = (float*)(ws + 66 * MB);        // raw sums, 256 floats
    float* ml    = (float*)(ws + 66 * MB + 65536);// 256KB
    short* Opart = (short*)(ws + 67 * MB);        // 32MB
    short* vTb   = (short*)(ws + 99 * MB);        // 16MB transposed v
    short* attn  = xn;
    short* kb    = qb + (size_t)BATCH * SEQ * CH;

    hipMemsetAsync(stats, 0, 256 * sizeof(float), stream);
    gn_partial_kernel<<<256, 256, 0, stream>>>(x, stats);
    gn_apply_kernel<<<8192, 256, 0, stream>>>(x, stats, gsc, gbs, xn);
    wtrans_kernel<<<dim3(16, 16, 4), dim3(32, 8), 0, stream>>>(wq, wk, wv, wo, wT);

    short* woT = wT + 786432;

    gemm_qkv_kernel<<<dim3(128, 12), 256, 0, stream>>>(xn, wT, bq, bk, bv, qb);
    vtrans_kernel<<<dim3(128, 16, 4), dim3(32, 8), 0, stream>>>(vraw, vTb);
    flash_kernel<<<dim3(64, 2, 4), 256, 0, stream>>>(qb, kb, vTb, Opart, ml);
    combine_kernel<<<4096, 256, 0, stream>>>(Opart, ml, attn);
    gemm_bt_kernel<<<dim3(128, 4), 256, 0, stream>>>(attn, woT, bo, out, x);
}

// Round 6
// 432.834 us; speedup vs baseline: 1.3753x; 1.2456x over previous
//
#include <hip/hip_runtime.h>
#include <hip/hip_bf16.h>
#include <stdint.h>

#define BATCH 4
#define SEQ   4096          // 64*64 spatial
#define CH    512
#define NGRP  32
#define GEPS  1e-6f

typedef short  short8  __attribute__((ext_vector_type(8)));
typedef float  floatx4 __attribute__((ext_vector_type(4)));

static __device__ __forceinline__ short bf16b(float f) {
    __hip_bfloat16 h = __float2bfloat16(f);
    return __builtin_bit_cast(short, h);
}
static __device__ __forceinline__ float bf2f(short s) {
    unsigned u = ((unsigned)(unsigned short)s) << 16;
    return __builtin_bit_cast(float, u);
}

// async global->LDS, 16B per lane. LDS dest = wave-uniform base + lane*16.
static __device__ __forceinline__ void dma16(const void* g, void* l) {
    __builtin_amdgcn_global_load_lds(
        (const __attribute__((address_space(1))) unsigned int*)g,
        (__attribute__((address_space(3))) unsigned int*)l, 16, 0, 0);
}

// max-reduce across the 16 lanes of a DPP row, pure VALU (no LDS traffic)
static __device__ __forceinline__ float rowmax16(float x) {
    int xi = __builtin_bit_cast(int, x);
    x = fmaxf(x, __builtin_bit_cast(float, __builtin_amdgcn_update_dpp(xi, xi, 0x128, 0xf, 0xf, true))); // row_ror:8
    xi = __builtin_bit_cast(int, x);
    x = fmaxf(x, __builtin_bit_cast(float, __builtin_amdgcn_update_dpp(xi, xi, 0x124, 0xf, 0xf, true))); // row_ror:4
    xi = __builtin_bit_cast(int, x);
    x = fmaxf(x, __builtin_bit_cast(float, __builtin_amdgcn_update_dpp(xi, xi, 0x122, 0xf, 0xf, true))); // row_ror:2
    xi = __builtin_bit_cast(int, x);
    x = fmaxf(x, __builtin_bit_cast(float, __builtin_amdgcn_update_dpp(xi, xi, 0x121, 0xf, 0xf, true))); // row_ror:1
    return x;
}

// ---------------- GroupNorm partial sums ----------------
__global__ __launch_bounds__(256) void gn_partial_kernel(const float* __restrict__ x,
                                                         float* __restrict__ statsraw) {
    int blk = blockIdx.x;                 // 0..255
    int t = threadIdx.x;
    size_t row0 = (size_t)blk * 64;
    int qd = t & 127;
    int rh = t >> 7;
    const float* base = x + row0 * 512 + qd * 4;
    float s1 = 0.f, s2 = 0.f;
    #pragma unroll 4
    for (int i = 0; i < 32; ++i) {
        int r = rh + i * 2;
        float4 v = *reinterpret_cast<const float4*>(base + (size_t)r * 512);
        s1 += v.x + v.y + v.z + v.w;
        s2 += v.x * v.x + v.y * v.y + v.z * v.z + v.w * v.w;
    }
    __shared__ float a1[256], a2[256];
    a1[t] = s1; a2[t] = s2;
    __syncthreads();
    if (t < 32) {
        float u1 = 0.f, u2 = 0.f;
        #pragma unroll
        for (int e = 0; e < 4; ++e) {
            u1 += a1[t * 4 + e] + a1[128 + t * 4 + e];
            u2 += a2[t * 4 + e] + a2[128 + t * 4 + e];
        }
        int b = (int)(row0 >> 12);
        atomicAdd(&statsraw[(b * 32 + t) * 2],     u1);
        atomicAdd(&statsraw[(b * 32 + t) * 2 + 1], u2);
    }
}

// ---------------- GroupNorm apply ----------------
__global__ __launch_bounds__(256) void gn_apply_kernel(const float* __restrict__ x,
                                                       const float* __restrict__ statsraw,
                                                       const float* __restrict__ gsc,
                                                       const float* __restrict__ gbs,
                                                       short* __restrict__ xn) {
    int i4 = blockIdx.x * 256 + threadIdx.x;
    int base = i4 * 4;
    int b = base >> 21;
    int c = base & 511;
    int sidx = (b * 32 + (c >> 4)) * 2;
    float s1 = statsraw[sidx], s2 = statsraw[sidx + 1];
    float mean = s1 * (1.f / 65536.f);
    float var  = s2 * (1.f / 65536.f) - mean * mean;
    float rstd = rsqrtf(var + GEPS);
    float4 xv = reinterpret_cast<const float4*>(x)[i4];
    float4 sv = *reinterpret_cast<const float4*>(gsc + c);
    float4 bv = *reinterpret_cast<const float4*>(gbs + c);
    union { short s[4]; uint2 u; } p;
    p.s[0] = bf16b((xv.x - mean) * rstd * sv.x + bv.x);
    p.s[1] = bf16b((xv.y - mean) * rstd * sv.y + bv.y);
    p.s[2] = bf16b((xv.z - mean) * rstd * sv.z + bv.z);
    p.s[3] = bf16b((xv.w - mean) * rstd * sv.w + bv.w);
    reinterpret_cast<uint2*>(xn)[i4] = p.u;
}

// ---------------- weight transpose ----------------
__global__ __launch_bounds__(256) void wtrans_kernel(const float* __restrict__ w0,
                                                     const float* __restrict__ w1,
                                                     const float* __restrict__ w2,
                                                     const float* __restrict__ w3,
                                                     short* __restrict__ wT) {
    const float* w = (blockIdx.z == 0) ? w0 : (blockIdx.z == 1) ? w1
                   : (blockIdx.z == 2) ? w2 : w3;
    short* out = wT + (size_t)blockIdx.z * CH * CH;
    int n0 = blockIdx.x * 32, k0 = blockIdx.y * 32;
    int tx = threadIdx.x, ty = threadIdx.y;
    __shared__ float s[32][33];
    #pragma unroll
    for (int i = 0; i < 4; ++i) {
        int kk = ty + i * 8;
        s[kk][tx] = w[(size_t)(k0 + kk) * CH + n0 + tx];
    }
    __syncthreads();
    #pragma unroll
    for (int i = 0; i < 4; ++i) {
        int nn = ty + i * 8;
        out[(size_t)(n0 + nn) * CH + k0 + tx] = bf16b(s[tx][nn]);
    }
}

// ---------------- v transpose ----------------
__global__ __launch_bounds__(256) void vtrans_kernel(const short* __restrict__ v,
                                                     short* __restrict__ vT) {
    int b = blockIdx.z;
    int l0 = blockIdx.x * 32, d0 = blockIdx.y * 32;
    int tx = threadIdx.x, ty = threadIdx.y;
    __shared__ short s[32][33];
    #pragma unroll
    for (int i = 0; i < 4; ++i) {
        int ll = ty + i * 8;
        s[ll][tx] = v[((size_t)b * SEQ + l0 + ll) * CH + d0 + tx];
    }
    __syncthreads();
    #pragma unroll
    for (int i = 0; i < 4; ++i) {
        int dd = ty + i * 8;
        vT[((size_t)b * CH + d0 + dd) * SEQ + l0 + tx] = s[tx][dd];
    }
}

// ---------------- fused QKV GEMM ----------------
__global__ __launch_bounds__(256) void gemm_qkv_kernel(const short* __restrict__ A,
                                                       const short* __restrict__ wT,
                                                       const float* __restrict__ bq,
                                                       const float* __restrict__ bk,
                                                       const float* __restrict__ bv,
                                                       short* __restrict__ outbase) {
    __shared__ short As[128 * 64];
    __shared__ short Bs[128 * 64];
    int m0 = blockIdx.x * 128;
    int nblk = blockIdx.y;                  // 0..11
    int which = nblk >> 2;                  // 0=q,1=k,2=v (block-uniform)
    int n0 = (nblk & 3) * 128;
    const short* BT = wT + (size_t)which * 512 * 512;
    const float* bias = (which == 0) ? bq : (which == 1) ? bk : bv;
    short* outb = outbase + (size_t)which * BATCH * SEQ * 512;
    int t = threadIdx.x;
    int w = t >> 6, lane = t & 63;
    int wr = w >> 1, wc = w & 1;
    int l15 = lane & 15, l4 = lane >> 4;
    floatx4 acc[4][4];
    #pragma unroll
    for (int i = 0; i < 4; ++i)
        #pragma unroll
        for (int j = 0; j < 4; ++j) acc[i][j] = (floatx4){0.f, 0.f, 0.f, 0.f};

    for (int k0 = 0; k0 < 512; k0 += 64) {
        __syncthreads();
        #pragma unroll
        for (int i = 0; i < 4; ++i) {
            int c = i * 256 + t;
            int row = c >> 3, j = (c & 7) ^ (row & 7);
            dma16(&A[(size_t)(m0 + row) * 512 + k0 + j * 8], &As[(c & ~63) * 8]);
            dma16(&BT[(size_t)(n0 + row) * 512 + k0 + j * 8], &Bs[(c & ~63) * 8]);
        }
        __syncthreads();
        #pragma unroll
        for (int kk = 0; kk < 64; kk += 32) {
            short8 af[4], bf[4];
            #pragma unroll
            for (int i = 0; i < 4; ++i) {
                int row = wr * 64 + i * 16 + l15;
                int j = (kk >> 3) + l4;
                af[i] = *reinterpret_cast<const short8*>(&As[(row * 8 + (j ^ (l15 & 7))) * 8]);
            }
            #pragma unroll
            for (int j2 = 0; j2 < 4; ++j2) {
                int row = wc * 64 + j2 * 16 + l15;
                int j = (kk >> 3) + l4;
                bf[j2] = *reinterpret_cast<const short8*>(&Bs[(row * 8 + (j ^ (l15 & 7))) * 8]);
            }
            #pragma unroll
            for (int i = 0; i < 4; ++i)
                #pragma unroll
                for (int j2 = 0; j2 < 4; ++j2)
                    acc[i][j2] = __builtin_amdgcn_mfma_f32_16x16x32_bf16(af[i], bf[j2], acc[i][j2], 0, 0, 0);
        }
    }
    #pragma unroll
    for (int i = 0; i < 4; ++i)
        #pragma unroll
        for (int j = 0; j < 4; ++j)
            #pragma unroll
            for (int r = 0; r < 4; ++r) {
                int row = m0 + wr * 64 + i * 16 + l4 * 4 + r;
                int col = n0 + wc * 64 + j * 16 + l15;
                outb[(size_t)row * 512 + col] = bf16b(acc[i][j][r] + bias[col]);
            }
}

// ---------------- output GEMM: bias + residual, fp32 out ----------------
__global__ __launch_bounds__(256) void gemm_bt_kernel(const short* __restrict__ A,
                                                      const short* __restrict__ BT,
                                                      const float* __restrict__ bias,
                                                      float* __restrict__ outf,
                                                      const float* __restrict__ resid) {
    __shared__ short As[128 * 64];
    __shared__ short Bs[128 * 64];
    int m0 = blockIdx.x * 128, n0 = blockIdx.y * 128;
    int t = threadIdx.x;
    int w = t >> 6, lane = t & 63;
    int wr = w >> 1, wc = w & 1;
    int l15 = lane & 15, l4 = lane >> 4;
    floatx4 acc[4][4];
    #pragma unroll
    for (int i = 0; i < 4; ++i)
        #pragma unroll
        for (int j = 0; j < 4; ++j) acc[i][j] = (floatx4){0.f, 0.f, 0.f, 0.f};

    for (int k0 = 0; k0 < 512; k0 += 64) {
        __syncthreads();
        #pragma unroll
        for (int i = 0; i < 4; ++i) {
            int c = i * 256 + t;
            int row = c >> 3, j = (c & 7) ^ (row & 7);
            dma16(&A[(size_t)(m0 + row) * 512 + k0 + j * 8], &As[(c & ~63) * 8]);
            dma16(&BT[(size_t)(n0 + row) * 512 + k0 + j * 8], &Bs[(c & ~63) * 8]);
        }
        __syncthreads();
        #pragma unroll
        for (int kk = 0; kk < 64; kk += 32) {
            short8 af[4], bf[4];
            #pragma unroll
            for (int i = 0; i < 4; ++i) {
                int row = wr * 64 + i * 16 + l15;
                int j = (kk >> 3) + l4;
                af[i] = *reinterpret_cast<const short8*>(&As[(row * 8 + (j ^ (l15 & 7))) * 8]);
            }
            #pragma unroll
            for (int j2 = 0; j2 < 4; ++j2) {
                int row = wc * 64 + j2 * 16 + l15;
                int j = (kk >> 3) + l4;
                bf[j2] = *reinterpret_cast<const short8*>(&Bs[(row * 8 + (j ^ (l15 & 7))) * 8]);
            }
            #pragma unroll
            for (int i = 0; i < 4; ++i)
                #pragma unroll
                for (int j2 = 0; j2 < 4; ++j2)
                    acc[i][j2] = __builtin_amdgcn_mfma_f32_16x16x32_bf16(af[i], bf[j2], acc[i][j2], 0, 0, 0);
        }
    }
    #pragma unroll
    for (int i = 0; i < 4; ++i)
        #pragma unroll
        for (int j = 0; j < 4; ++j)
            #pragma unroll
            for (int r = 0; r < 4; ++r) {
                int row = m0 + wr * 64 + i * 16 + l4 * 4 + r;
                int col = n0 + wc * 64 + j * 16 + l15;
                float vv = acc[i][j][r] + bias[col];
                outf[(size_t)row * 512 + col] = vv + resid[(size_t)row * 512 + col];
            }
}

// ---------------- flash attention: pipelined double-buffer, 512 thr, q-block 128 ----
// grid (32, 2, 4) = 256 blocks = 1/CU. 8 waves; wave w owns q-rows [q0+w*16, +16).
// LDS (shorts): K buf0 [0,16384) buf1 [16384,32768); V buf0 [32768,49152) buf1 [49152,65536);
// P [65536,69632) = 8 waves x 512. One barrier per iter; DMA(i+1) issued before compute(i).
__global__ __launch_bounds__(512) void flash_kernel(const short* __restrict__ q,
                                                    const short* __restrict__ k,
                                                    const short* __restrict__ vT,
                                                    short* __restrict__ Opart,
                                                    float* __restrict__ ml) {
    __shared__ short smem[69632];   // 139,264 B
    int b = blockIdx.z;
    int part = blockIdx.y;
    int q0 = blockIdx.x * 128;
    int t = threadIdx.x, w = t >> 6, lane = t & 63;
    int l15 = lane & 15, l4 = lane >> 4;
    const float scale = 0.044194173824159216f;  // 1/sqrt(512)

    short8 qf[16];
    {
        const short* qrow = q + ((size_t)b * SEQ + q0 + w * 16 + l15) * 512;
        #pragma unroll
        for (int ks = 0; ks < 16; ++ks)
            qf[ks] = *reinterpret_cast<const short8*>(qrow + ks * 32 + l4 * 8);
    }

    floatx4 acc[32];
    #pragma unroll
    for (int i = 0; i < 32; ++i) acc[i] = (floatx4){0.f, 0.f, 0.f, 0.f};
    floatx4 lacc = (floatx4){0.f, 0.f, 0.f, 0.f};
    float mprev[4] = {-1e30f, -1e30f, -1e30f, -1e30f};

    short8 ones;
    #pragma unroll
    for (int j = 0; j < 8; ++j) ones[j] = (short)0x3F80;   // bf16 1.0

    const short* kbase = k  + (size_t)b * SEQ * 512;
    const short* vbase = vT + (size_t)b * 512 * SEQ;

    const int vswz = l4 ^ ((l15 >> 1) & 3);
    const int kswz = l15 & 7;
    const int s_begin = part * (SEQ / 2);

    // staging: K tile 2048 chunks, V tile 2048 chunks; 4 dma16 each per thread (512 thr)
    auto stage = [&](int s0, int buf) {
        const short* ksrc = kbase + (size_t)s0 * 512;
        #pragma unroll
        for (int i = 0; i < 4; ++i) {
            int c = i * 512 + t;
            int row = c >> 6, j = (c & 63) ^ (row & 7);
            dma16(ksrc + row * 512 + j * 8, &smem[buf * 16384 + (c & ~63) * 8]);
        }
        #pragma unroll
        for (int i = 0; i < 4; ++i) {
            int c = i * 512 + t;
            int d = c >> 2, jv = (c & 3) ^ ((d >> 1) & 3);
            dma16(vbase + (size_t)d * SEQ + s0 + jv * 8, &smem[32768 + buf * 16384 + (c & ~63) * 8]);
        }
    };

    stage(s_begin, 0);
    __syncthreads();                                   // tile 0 ready

    for (int it = 0; it < 64; ++it) {
        int cur = it & 1;
        if (it + 1 < 64) stage(s_begin + (it + 1) * 32, 1 - cur);

        const short* Kb = smem + cur * 16384;
        const short* Vb = smem + 32768 + cur * 16384;

        // --- QK^T : S[16 rows][32 cols] in two 16x16 C-tiles
        floatx4 sa0 = (floatx4){0.f, 0.f, 0.f, 0.f};
        floatx4 sa1 = (floatx4){0.f, 0.f, 0.f, 0.f};
        #pragma unroll
        for (int ks = 0; ks < 16; ++ks) {
            int js = (ks * 4 + l4) ^ kswz;
            short8 b0 = *reinterpret_cast<const short8*>(&Kb[(l15 * 64 + js) * 8]);
            short8 b1 = *reinterpret_cast<const short8*>(&Kb[((l15 + 16) * 64 + js) * 8]);
            sa0 = __builtin_amdgcn_mfma_f32_16x16x32_bf16(qf[ks], b0, sa0, 0, 0, 0);
            sa1 = __builtin_amdgcn_mfma_f32_16x16x32_bf16(qf[ks], b1, sa1, 0, 0, 0);
        }

        // --- online softmax (own 16 rows)
        float p0[4], p1[4], alpha[4];
        bool changed = false;
        #pragma unroll
        for (int r = 0; r < 4; ++r) {
            float v0 = sa0[r] * scale, v1 = sa1[r] * scale;
            float mx = rowmax16(fmaxf(v0, v1));
            float nm = fmaxf(mprev[r], mx);
            alpha[r] = __expf(mprev[r] - nm);
            changed |= (nm > mprev[r]);
            p0[r] = __expf(v0 - nm);
            p1[r] = __expf(v1 - nm);
            mprev[r] = nm;
        }
        if (__ballot(changed)) {
            #pragma unroll
            for (int i = 0; i < 32; ++i)
                #pragma unroll
                for (int r = 0; r < 4; ++r) acc[i][r] *= alpha[r];
            #pragma unroll
            for (int r = 0; r < 4; ++r) lacc[r] *= alpha[r];
        }

        // P write/read: wave-private region, no barrier needed around it
        short* Ps = smem + 65536 + w * 512;
        #pragma unroll
        for (int r = 0; r < 4; ++r) {
            Ps[(l4 * 4 + r) * 32 + l15]      = bf16b(p0[r]);
            Ps[(l4 * 4 + r) * 32 + 16 + l15] = bf16b(p1[r]);
        }

        short8 pf = *reinterpret_cast<const short8*>(Ps + l15 * 32 + l4 * 8);
        lacc = __builtin_amdgcn_mfma_f32_16x16x32_bf16(pf, ones, lacc, 0, 0, 0);
        #pragma unroll
        for (int tt = 0; tt < 32; ++tt) {
            int d = tt * 16 + l15;
            short8 vf = *reinterpret_cast<const short8*>(&Vb[(d * 4 + vswz) * 8]);
            acc[tt] = __builtin_amdgcn_mfma_f32_16x16x32_bf16(pf, vf, acc[tt], 0, 0, 0);
        }

        __syncthreads();    // drains DMA(i+1) (vmcnt0) + all reads of buf[cur] done
    }

    short* obase = Opart + (((size_t)part * BATCH + b) * SEQ + q0 + w * 16) * 512;
    #pragma unroll
    for (int r = 0; r < 4; ++r) {
        #pragma unroll
        for (int tt = 0; tt < 32; ++tt)
            obase[(size_t)(l4 * 4 + r) * 512 + tt * 16 + l15] = bf16b(acc[tt][r]);
    }
    if (l15 == 0) {
        #pragma unroll
        for (int r = 0; r < 4; ++r) {
            size_t rowg = ((size_t)part * BATCH + b) * SEQ + q0 + w * 16 + l4 * 4 + r;
            ml[rowg * 2]     = mprev[r];
            ml[rowg * 2 + 1] = lacc[r];
        }
    }
}

// ---------------- combine ----------------
__global__ __launch_bounds__(256) void combine_kernel(const short* __restrict__ Opart,
                                                      const float* __restrict__ ml,
                                                      short* __restrict__ attn) {
    int i8 = blockIdx.x * 256 + threadIdx.x;
    size_t row = (size_t)i8 >> 6;
    float m0 = ml[row * 2], l0 = ml[row * 2 + 1];
    float m1 = ml[((size_t)BATCH * SEQ + row) * 2], l1 = ml[((size_t)BATCH * SEQ + row) * 2 + 1];
    float m = fmaxf(m0, m1);
    float e0 = __expf(m0 - m), e1 = __expf(m1 - m);
    float inv = 1.f / (e0 * l0 + e1 * l1);
    e0 *= inv; e1 *= inv;
    union { uint4 u; short s[8]; } a, bb, o;
    a.u  = reinterpret_cast<const uint4*>(Opart)[i8];
    bb.u = reinterpret_cast<const uint4*>(Opart)[(size_t)BATCH * SEQ * 512 / 8 + i8];
    #pragma unroll
    for (int e = 0; e < 8; ++e)
        o.s[e] = bf16b(bf2f(a.s[e]) * e0 + bf2f(bb.s[e]) * e1);
    reinterpret_cast<uint4*>(attn)[i8] = o.u;
}

extern "C" void kernel_launch(void* const* d_in, const int* in_sizes, int n_in,
                              void* d_out, int out_size, void* d_ws, size_t ws_size,
                              hipStream_t stream) {
    const float* x   = (const float*)d_in[0];
    const float* gsc = (const float*)d_in[1];
    const float* gbs = (const float*)d_in[2];
    const float* wq  = (const float*)d_in[3];
    const float* bq  = (const float*)d_in[4];
    const float* wk  = (const float*)d_in[5];
    const float* bk  = (const float*)d_in[6];
    const float* wv  = (const float*)d_in[7];
    const float* bv  = (const float*)d_in[8];
    const float* wo  = (const float*)d_in[9];
    const float* bo  = (const float*)d_in[10];
    float* out = (float*)d_out;

    char* ws = (char*)d_ws;
    const size_t MB = 1ull << 20;
    short* xn    = (short*)ws;                    // 16MB; reused as attn (combine output)
    short* qb    = (short*)(ws + 16 * MB);        // q(16) k(16) v(16) contiguous -> fused GEMM
    short* vraw  = (short*)(ws + 48 * MB);        // raw v (fused GEMM which=2 lands here)
    short* wT    = (short*)(ws + 64 * MB);        // 2MB: 4 x [512][512] bf16
    float* stats = (float*)(ws + 66 * MB);        // raw sums, 256 floats
    float* ml    = (float*)(ws + 66 * MB + 65536);// 256KB
    short* Opart = (short*)(ws + 67 * MB);        // 32MB
    short* vTb   = (short*)(ws + 99 * MB);        // 16MB transposed v
    short* attn  = xn;
    short* kb    = qb + (size_t)BATCH * SEQ * CH;

    hipMemsetAsync(stats, 0, 256 * sizeof(float), stream);
    gn_partial_kernel<<<256, 256, 0, stream>>>(x, stats);
    gn_apply_kernel<<<8192, 256, 0, stream>>>(x, stats, gsc, gbs, xn);
    wtrans_kernel<<<dim3(16, 16, 4), dim3(32, 8), 0, stream>>>(wq, wk, wv, wo, wT);

    short* woT = wT + 786432;

    gemm_qkv_kernel<<<dim3(128, 12), 256, 0, stream>>>(xn, wT, bq, bk, bv, qb);
    vtrans_kernel<<<dim3(128, 16, 4), dim3(32, 8), 0, stream>>>(vraw, vTb);
    flash_kernel<<<dim3(32, 2, 4), 512, 0, stream>>>(qb, kb, vTb, Opart, ml);
    combine_kernel<<<4096, 256, 0, stream>>>(Opart, ml, attn);
    gemm_bt_kernel<<<dim3(128, 4), 256, 0, stream>>>(attn, woT, bo, out, x);
}

// Round 7
// 359.268 us; speedup vs baseline: 1.6569x; 1.2048x over previous
//
#include <hip/hip_runtime.h>
#include <hip/hip_bf16.h>
#include <stdint.h>

#define BATCH 4
#define SEQ   4096          // 64*64 spatial
#define CH    512
#define NGRP  32
#define GEPS  1e-6f

typedef short  short8  __attribute__((ext_vector_type(8)));
typedef float  floatx4 __attribute__((ext_vector_type(4)));

static __device__ __forceinline__ short bf16b(float f) {
    __hip_bfloat16 h = __float2bfloat16(f);
    return __builtin_bit_cast(short, h);
}
static __device__ __forceinline__ float bf2f(short s) {
    unsigned u = ((unsigned)(unsigned short)s) << 16;
    return __builtin_bit_cast(float, u);
}

// async global->LDS, 16B per lane. LDS dest = wave-uniform base + lane*16.
static __device__ __forceinline__ void dma16(const void* g, void* l) {
    __builtin_amdgcn_global_load_lds(
        (const __attribute__((address_space(1))) unsigned int*)g,
        (__attribute__((address_space(3))) unsigned int*)l, 16, 0, 0);
}

// max-reduce across the 16 lanes of a DPP row, pure VALU
static __device__ __forceinline__ float rowmax16(float x) {
    int xi = __builtin_bit_cast(int, x);
    x = fmaxf(x, __builtin_bit_cast(float, __builtin_amdgcn_update_dpp(xi, xi, 0x128, 0xf, 0xf, true))); // row_ror:8
    xi = __builtin_bit_cast(int, x);
    x = fmaxf(x, __builtin_bit_cast(float, __builtin_amdgcn_update_dpp(xi, xi, 0x124, 0xf, 0xf, true))); // row_ror:4
    xi = __builtin_bit_cast(int, x);
    x = fmaxf(x, __builtin_bit_cast(float, __builtin_amdgcn_update_dpp(xi, xi, 0x122, 0xf, 0xf, true))); // row_ror:2
    xi = __builtin_bit_cast(int, x);
    x = fmaxf(x, __builtin_bit_cast(float, __builtin_amdgcn_update_dpp(xi, xi, 0x121, 0xf, 0xf, true))); // row_ror:1
    return x;
}

// ---------------- GroupNorm partial sums ----------------
__global__ __launch_bounds__(256) void gn_partial_kernel(const float* __restrict__ x,
                                                         float* __restrict__ statsraw) {
    int blk = blockIdx.x;                 // 0..255
    int t = threadIdx.x;
    size_t row0 = (size_t)blk * 64;
    int qd = t & 127;
    int rh = t >> 7;
    const float* base = x + row0 * 512 + qd * 4;
    float s1 = 0.f, s2 = 0.f;
    #pragma unroll 4
    for (int i = 0; i < 32; ++i) {
        int r = rh + i * 2;
        float4 v = *reinterpret_cast<const float4*>(base + (size_t)r * 512);
        s1 += v.x + v.y + v.z + v.w;
        s2 += v.x * v.x + v.y * v.y + v.z * v.z + v.w * v.w;
    }
    __shared__ float a1[256], a2[256];
    a1[t] = s1; a2[t] = s2;
    __syncthreads();
    if (t < 32) {
        float u1 = 0.f, u2 = 0.f;
        #pragma unroll
        for (int e = 0; e < 4; ++e) {
            u1 += a1[t * 4 + e] + a1[128 + t * 4 + e];
            u2 += a2[t * 4 + e] + a2[128 + t * 4 + e];
        }
        int b = (int)(row0 >> 12);
        atomicAdd(&statsraw[(b * 32 + t) * 2],     u1);
        atomicAdd(&statsraw[(b * 32 + t) * 2 + 1], u2);
    }
}

// ---------------- GroupNorm apply ----------------
__global__ __launch_bounds__(256) void gn_apply_kernel(const float* __restrict__ x,
                                                       const float* __restrict__ statsraw,
                                                       const float* __restrict__ gsc,
                                                       const float* __restrict__ gbs,
                                                       short* __restrict__ xn) {
    int i4 = blockIdx.x * 256 + threadIdx.x;
    int base = i4 * 4;
    int b = base >> 21;
    int c = base & 511;
    int sidx = (b * 32 + (c >> 4)) * 2;
    float s1 = statsraw[sidx], s2 = statsraw[sidx + 1];
    float mean = s1 * (1.f / 65536.f);
    float var  = s2 * (1.f / 65536.f) - mean * mean;
    float rstd = rsqrtf(var + GEPS);
    float4 xv = reinterpret_cast<const float4*>(x)[i4];
    float4 sv = *reinterpret_cast<const float4*>(gsc + c);
    float4 bv = *reinterpret_cast<const float4*>(gbs + c);
    union { short s[4]; uint2 u; } p;
    p.s[0] = bf16b((xv.x - mean) * rstd * sv.x + bv.x);
    p.s[1] = bf16b((xv.y - mean) * rstd * sv.y + bv.y);
    p.s[2] = bf16b((xv.z - mean) * rstd * sv.z + bv.z);
    p.s[3] = bf16b((xv.w - mean) * rstd * sv.w + bv.w);
    reinterpret_cast<uint2*>(xn)[i4] = p.u;
}

// ---------------- weight transpose ----------------
__global__ __launch_bounds__(256) void wtrans_kernel(const float* __restrict__ w0,
                                                     const float* __restrict__ w1,
                                                     const float* __restrict__ w2,
                                                     const float* __restrict__ w3,
                                                     short* __restrict__ wT) {
    const float* w = (blockIdx.z == 0) ? w0 : (blockIdx.z == 1) ? w1
                   : (blockIdx.z == 2) ? w2 : w3;
    short* out = wT + (size_t)blockIdx.z * CH * CH;
    int n0 = blockIdx.x * 32, k0 = blockIdx.y * 32;
    int tx = threadIdx.x, ty = threadIdx.y;
    __shared__ float s[32][33];
    #pragma unroll
    for (int i = 0; i < 4; ++i) {
        int kk = ty + i * 8;
        s[kk][tx] = w[(size_t)(k0 + kk) * CH + n0 + tx];
    }
    __syncthreads();
    #pragma unroll
    for (int i = 0; i < 4; ++i) {
        int nn = ty + i * 8;
        out[(size_t)(n0 + nn) * CH + k0 + tx] = bf16b(s[tx][nn]);
    }
}

// ---------------- v transpose + fp8 convert: v[b][l][d] bf16 -> vT8[b][d][l] e4m3 ----
__global__ __launch_bounds__(256) void vtrans_kernel(const short* __restrict__ v,
                                                     char* __restrict__ vT8) {
    int b = blockIdx.z;
    int l0 = blockIdx.x * 32, d0 = blockIdx.y * 32;
    int tx = threadIdx.x, ty = threadIdx.y;
    __shared__ short s[32][33];
    #pragma unroll
    for (int i = 0; i < 4; ++i) {
        int ll = ty + i * 8;
        s[ll][tx] = v[((size_t)b * SEQ + l0 + ll) * CH + d0 + tx];
    }
    __syncthreads();
    #pragma unroll
    for (int i = 0; i < 4; ++i) {
        int dd = ty + i * 8;
        float val = bf2f(s[tx][dd]);
        int pk = __builtin_amdgcn_cvt_pk_fp8_f32(val, 0.f, 0, false);
        vT8[((size_t)b * CH + d0 + dd) * SEQ + l0 + tx] = (char)(pk & 0xff);
    }
}

// ---------------- bf16 -> fp8 e4m3 bulk convert (q and k, contiguous) ----------------
__global__ __launch_bounds__(256) void convert_fp8_kernel(const short* __restrict__ in,
                                                          char* __restrict__ out) {
    int i8 = blockIdx.x * 256 + threadIdx.x;    // 8 elems per thread
    union { uint4 u; short s[8]; } a;
    a.u = reinterpret_cast<const uint4*>(in)[i8];
    float f[8];
    #pragma unroll
    for (int e = 0; e < 8; ++e) f[e] = bf2f(a.s[e]);
    int lo = __builtin_amdgcn_cvt_pk_fp8_f32(f[0], f[1], 0, false);
    lo     = __builtin_amdgcn_cvt_pk_fp8_f32(f[2], f[3], lo, true);
    int hi = __builtin_amdgcn_cvt_pk_fp8_f32(f[4], f[5], 0, false);
    hi     = __builtin_amdgcn_cvt_pk_fp8_f32(f[6], f[7], hi, true);
    reinterpret_cast<int2*>(out)[i8] = make_int2(lo, hi);
}

// ---------------- fused QKV GEMM (bf16 out) ----------------
__global__ __launch_bounds__(256) void gemm_qkv_kernel(const short* __restrict__ A,
                                                       const short* __restrict__ wT,
                                                       const float* __restrict__ bq,
                                                       const float* __restrict__ bk,
                                                       const float* __restrict__ bv,
                                                       short* __restrict__ outbase) {
    __shared__ short As[128 * 64];
    __shared__ short Bs[128 * 64];
    int m0 = blockIdx.x * 128;
    int nblk = blockIdx.y;                  // 0..11
    int which = nblk >> 2;                  // 0=q,1=k,2=v
    int n0 = (nblk & 3) * 128;
    const short* BT = wT + (size_t)which * 512 * 512;
    const float* bias = (which == 0) ? bq : (which == 1) ? bk : bv;
    short* outb = outbase + (size_t)which * BATCH * SEQ * 512;
    int t = threadIdx.x;
    int w = t >> 6, lane = t & 63;
    int wr = w >> 1, wc = w & 1;
    int l15 = lane & 15, l4 = lane >> 4;
    floatx4 acc[4][4];
    #pragma unroll
    for (int i = 0; i < 4; ++i)
        #pragma unroll
        for (int j = 0; j < 4; ++j) acc[i][j] = (floatx4){0.f, 0.f, 0.f, 0.f};

    for (int k0 = 0; k0 < 512; k0 += 64) {
        __syncthreads();
        #pragma unroll
        for (int i = 0; i < 4; ++i) {
            int c = i * 256 + t;
            int row = c >> 3, j = (c & 7) ^ (row & 7);
            dma16(&A[(size_t)(m0 + row) * 512 + k0 + j * 8], &As[(c & ~63) * 8]);
            dma16(&BT[(size_t)(n0 + row) * 512 + k0 + j * 8], &Bs[(c & ~63) * 8]);
        }
        __syncthreads();
        #pragma unroll
        for (int kk = 0; kk < 64; kk += 32) {
            short8 af[4], bf[4];
            #pragma unroll
            for (int i = 0; i < 4; ++i) {
                int row = wr * 64 + i * 16 + l15;
                int j = (kk >> 3) + l4;
                af[i] = *reinterpret_cast<const short8*>(&As[(row * 8 + (j ^ (l15 & 7))) * 8]);
            }
            #pragma unroll
            for (int j2 = 0; j2 < 4; ++j2) {
                int row = wc * 64 + j2 * 16 + l15;
                int j = (kk >> 3) + l4;
                bf[j2] = *reinterpret_cast<const short8*>(&Bs[(row * 8 + (j ^ (l15 & 7))) * 8]);
            }
            #pragma unroll
            for (int i = 0; i < 4; ++i)
                #pragma unroll
                for (int j2 = 0; j2 < 4; ++j2)
                    acc[i][j2] = __builtin_amdgcn_mfma_f32_16x16x32_bf16(af[i], bf[j2], acc[i][j2], 0, 0, 0);
        }
    }
    #pragma unroll
    for (int i = 0; i < 4; ++i)
        #pragma unroll
        for (int j = 0; j < 4; ++j)
            #pragma unroll
            for (int r = 0; r < 4; ++r) {
                int row = m0 + wr * 64 + i * 16 + l4 * 4 + r;
                int col = n0 + wc * 64 + j * 16 + l15;
                outb[(size_t)row * 512 + col] = bf16b(acc[i][j][r] + bias[col]);
            }
}

// ---------------- output GEMM: bias + residual, fp32 out ----------------
__global__ __launch_bounds__(256) void gemm_bt_kernel(const short* __restrict__ A,
                                                      const short* __restrict__ BT,
                                                      const float* __restrict__ bias,
                                                      float* __restrict__ outf,
                                                      const float* __restrict__ resid) {
    __shared__ short As[128 * 64];
    __shared__ short Bs[128 * 64];
    int m0 = blockIdx.x * 128, n0 = blockIdx.y * 128;
    int t = threadIdx.x;
    int w = t >> 6, lane = t & 63;
    int wr = w >> 1, wc = w & 1;
    int l15 = lane & 15, l4 = lane >> 4;
    floatx4 acc[4][4];
    #pragma unroll
    for (int i = 0; i < 4; ++i)
        #pragma unroll
        for (int j = 0; j < 4; ++j) acc[i][j] = (floatx4){0.f, 0.f, 0.f, 0.f};

    for (int k0 = 0; k0 < 512; k0 += 64) {
        __syncthreads();
        #pragma unroll
        for (int i = 0; i < 4; ++i) {
            int c = i * 256 + t;
            int row = c >> 3, j = (c & 7) ^ (row & 7);
            dma16(&A[(size_t)(m0 + row) * 512 + k0 + j * 8], &As[(c & ~63) * 8]);
            dma16(&BT[(size_t)(n0 + row) * 512 + k0 + j * 8], &Bs[(c & ~63) * 8]);
        }
        __syncthreads();
        #pragma unroll
        for (int kk = 0; kk < 64; kk += 32) {
            short8 af[4], bf[4];
            #pragma unroll
            for (int i = 0; i < 4; ++i) {
                int row = wr * 64 + i * 16 + l15;
                int j = (kk >> 3) + l4;
                af[i] = *reinterpret_cast<const short8*>(&As[(row * 8 + (j ^ (l15 & 7))) * 8]);
            }
            #pragma unroll
            for (int j2 = 0; j2 < 4; ++j2) {
                int row = wc * 64 + j2 * 16 + l15;
                int j = (kk >> 3) + l4;
                bf[j2] = *reinterpret_cast<const short8*>(&Bs[(row * 8 + (j ^ (l15 & 7))) * 8]);
            }
            #pragma unroll
            for (int i = 0; i < 4; ++i)
                #pragma unroll
                for (int j2 = 0; j2 < 4; ++j2)
                    acc[i][j2] = __builtin_amdgcn_mfma_f32_16x16x32_bf16(af[i], bf[j2], acc[i][j2], 0, 0, 0);
        }
    }
    #pragma unroll
    for (int i = 0; i < 4; ++i)
        #pragma unroll
        for (int j = 0; j < 4; ++j)
            #pragma unroll
            for (int r = 0; r < 4; ++r) {
                int row = m0 + wr * 64 + i * 16 + l4 * 4 + r;
                int col = n0 + wc * 64 + j * 16 + l15;
                float vv = acc[i][j][r] + bias[col];
                outf[(size_t)row * 512 + col] = vv + resid[(size_t)row * 512 + col];
            }
}

// ---------------- flash attention: fp8 operands, pipelined dbuf, 512 thr ----------
// q8[b][l][d], k8[b][s][d], v8[b][d][s] all e4m3. S/softmax/O in fp32, Opart bf16.
// LDS bytes: K bufs [0,16384)+[16384,32768); V bufs [32768,49152)+[49152,65536);
// P [65536, 65536+8*640). One barrier/iter; DMA(i+1) issued before compute(i).
__global__ __launch_bounds__(512) void flash_kernel(const char* __restrict__ q8,
                                                    const char* __restrict__ k8,
                                                    const char* __restrict__ v8,
                                                    short* __restrict__ Opart,
                                                    float* __restrict__ ml) {
    __shared__ __align__(16) char smem[70656];
    int b = blockIdx.z;
    int part = blockIdx.y;
    int q0 = blockIdx.x * 128;
    int t = threadIdx.x, w = t >> 6, lane = t & 63;
    int l15 = lane & 15, l4 = lane >> 4;
    const float scale = 0.044194173824159216f;  // 1/sqrt(512)

    // Q fp8 fragments: rows w*16 + l15, all 512 k (8 bytes per ks-step)
    long qf[16];
    {
        const char* qrow = q8 + ((size_t)b * SEQ + q0 + w * 16 + l15) * 512;
        #pragma unroll
        for (int ks = 0; ks < 16; ++ks)
            qf[ks] = *reinterpret_cast<const long*>(qrow + ks * 32 + l4 * 8);
    }

    floatx4 acc[32];
    #pragma unroll
    for (int i = 0; i < 32; ++i) acc[i] = (floatx4){0.f, 0.f, 0.f, 0.f};
    floatx4 lacc = (floatx4){0.f, 0.f, 0.f, 0.f};
    float mprev[4] = {-1e30f, -1e30f, -1e30f, -1e30f};

    const long ones = 0x3838383838383838L;   // e4m3 1.0 x8

    const char* kbase = k8 + (size_t)b * SEQ * 512;
    const char* vbase = v8 + (size_t)b * 512 * SEQ;

    const int kswz = l15 & 7;                       // K read swizzle
    const int vswz = (l4 >> 1) ^ ((l15 >> 2) & 1);  // V read chunk swizzle
    const int koff = (l4 & 1) * 8;
    const int s_begin = part * (SEQ / 2);

    // stage: K tile 32 rows x 512 B (1024 16B-chunks), V tile 512 rows x 32 B (1024 chunks)
    auto stage = [&](int s0, int buf) {
        char* Kd = smem + buf * 16384;
        char* Vd = smem + 32768 + buf * 16384;
        #pragma unroll
        for (int i = 0; i < 2; ++i) {
            int c = i * 512 + t;
            int row = c >> 5, j = (c & 31) ^ (row & 7);
            dma16(kbase + (size_t)(s0 + row) * 512 + j * 16, Kd + (size_t)(c & ~63) * 16);
        }
        #pragma unroll
        for (int i = 0; i < 2; ++i) {
            int c = i * 512 + t;
            int d = c >> 1, j = (c & 1) ^ ((d >> 2) & 1);
            dma16(vbase + (size_t)d * SEQ + s0 + j * 16, Vd + (size_t)(c & ~63) * 16);
        }
    };

    stage(s_begin, 0);
    __syncthreads();                                   // tile 0 ready

    for (int it = 0; it < 64; ++it) {
        int cur = it & 1;
        if (it + 1 < 64) stage(s_begin + (it + 1) * 32, 1 - cur);

        const char* Kb = smem + cur * 16384;
        const char* Vb = smem + 32768 + cur * 16384;

        // --- QK^T (fp8): S[16 rows][32 cols] in two 16x16 C-tiles
        floatx4 sa0 = (floatx4){0.f, 0.f, 0.f, 0.f};
        floatx4 sa1 = (floatx4){0.f, 0.f, 0.f, 0.f};
        #pragma unroll
        for (int ks = 0; ks < 16; ++ks) {
            int jc = ks * 2 + (l4 >> 1);
            int a0 = (l15 * 32 + (jc ^ kswz)) * 16 + koff;
            long b0 = *reinterpret_cast<const long*>(Kb + a0);
            long b1 = *reinterpret_cast<const long*>(Kb + a0 + 8192);
            sa0 = __builtin_amdgcn_mfma_f32_16x16x32_fp8_fp8(qf[ks], b0, sa0, 0, 0, 0);
            sa1 = __builtin_amdgcn_mfma_f32_16x16x32_fp8_fp8(qf[ks], b1, sa1, 0, 0, 0);
        }

        // --- online softmax (own 16 rows)
        float p0[4], p1[4], alpha[4];
        bool changed = false;
        #pragma unroll
        for (int r = 0; r < 4; ++r) {
            float v0 = sa0[r] * scale, v1 = sa1[r] * scale;
            float mx = rowmax16(fmaxf(v0, v1));
            float nm = fmaxf(mprev[r], mx);
            alpha[r] = __expf(mprev[r] - nm);
            changed |= (nm > mprev[r]);
            p0[r] = __expf(v0 - nm);
            p1[r] = __expf(v1 - nm);
            mprev[r] = nm;
        }
        if (__ballot(changed)) {
            #pragma unroll
            for (int i = 0; i < 32; ++i)
                #pragma unroll
                for (int r = 0; r < 4; ++r) acc[i][r] *= alpha[r];
            #pragma unroll
            for (int r = 0; r < 4; ++r) lacc[r] *= alpha[r];
        }

        // P (fp8) write to wave-private region: row pitch 40 B breaks bank conflicts
        char* Ps = smem + 65536 + w * 640;
        #pragma unroll
        for (int r = 0; r < 4; ++r) {
            int pk = __builtin_amdgcn_cvt_pk_fp8_f32(p0[r], p1[r], 0, false);
            Ps[(l4 * 4 + r) * 40 + l15]      = (char)(pk & 0xff);
            Ps[(l4 * 4 + r) * 40 + 16 + l15] = (char)((pk >> 8) & 0xff);
        }

        long pf = *reinterpret_cast<const long*>(Ps + l15 * 40 + l4 * 8);
        lacc = __builtin_amdgcn_mfma_f32_16x16x32_fp8_fp8(pf, ones, lacc, 0, 0, 0);
        #pragma unroll
        for (int tt = 0; tt < 32; ++tt) {
            int d = tt * 16 + l15;
            long vf = *reinterpret_cast<const long*>(Vb + (d * 2 + vswz) * 16 + koff);
            acc[tt] = __builtin_amdgcn_mfma_f32_16x16x32_fp8_fp8(pf, vf, acc[tt], 0, 0, 0);
        }

        __syncthreads();    // drains DMA(i+1) + all reads of buf[cur] done
    }

    short* obase = Opart + (((size_t)part * BATCH + b) * SEQ + q0 + w * 16) * 512;
    #pragma unroll
    for (int r = 0; r < 4; ++r) {
        #pragma unroll
        for (int tt = 0; tt < 32; ++tt)
            obase[(size_t)(l4 * 4 + r) * 512 + tt * 16 + l15] = bf16b(acc[tt][r]);
    }
    if (l15 == 0) {
        #pragma unroll
        for (int r = 0; r < 4; ++r) {
            size_t rowg = ((size_t)part * BATCH + b) * SEQ + q0 + w * 16 + l4 * 4 + r;
            ml[rowg * 2]     = mprev[r];
            ml[rowg * 2 + 1] = lacc[r];
        }
    }
}

// ---------------- combine ----------------
__global__ __launch_bounds__(256) void combine_kernel(const short* __restrict__ Opart,
                                                      const float* __restrict__ ml,
                                                      short* __restrict__ attn) {
    int i8 = blockIdx.x * 256 + threadIdx.x;
    size_t row = (size_t)i8 >> 6;
    float m0 = ml[row * 2], l0 = ml[row * 2 + 1];
    float m1 = ml[((size_t)BATCH * SEQ + row) * 2], l1 = ml[((size_t)BATCH * SEQ + row) * 2 + 1];
    float m = fmaxf(m0, m1);
    float e0 = __expf(m0 - m), e1 = __expf(m1 - m);
    float inv = 1.f / (e0 * l0 + e1 * l1);
    e0 *= inv; e1 *= inv;
    union { uint4 u; short s[8]; } a, bb, o;
    a.u  = reinterpret_cast<const uint4*>(Opart)[i8];
    bb.u = reinterpret_cast<const uint4*>(Opart)[(size_t)BATCH * SEQ * 512 / 8 + i8];
    #pragma unroll
    for (int e = 0; e < 8; ++e)
        o.s[e] = bf16b(bf2f(a.s[e]) * e0 + bf2f(bb.s[e]) * e1);
    reinterpret_cast<uint4*>(attn)[i8] = o.u;
}

extern "C" void kernel_launch(void* const* d_in, const int* in_sizes, int n_in,
                              void* d_out, int out_size, void* d_ws, size_t ws_size,
                              hipStream_t stream) {
    const float* x   = (const float*)d_in[0];
    const float* gsc = (const float*)d_in[1];
    const float* gbs = (const float*)d_in[2];
    const float* wq  = (const float*)d_in[3];
    const float* bq  = (const float*)d_in[4];
    const float* wk  = (const float*)d_in[5];
    const float* bk  = (const float*)d_in[6];
    const float* wv  = (const float*)d_in[7];
    const float* bv  = (const float*)d_in[8];
    const float* wo  = (const float*)d_in[9];
    const float* bo  = (const float*)d_in[10];
    float* out = (float*)d_out;

    char* ws = (char*)d_ws;
    const size_t MB = 1ull << 20;
    // [0,16)   xn bf16 during GEMMs -> then q8(8MB)+k8(8MB) fp8 -> then attn bf16 (combine out)
    // [16,64)  qb/kb/vraw bf16 (fused QKV GEMM out, contiguous)
    // [64,66)  wT; [66, ..) stats + ml; [67,99) Opart; [99,107) vT8 fp8
    short* xn    = (short*)ws;
    short* qb    = (short*)(ws + 16 * MB);
    short* vraw  = (short*)(ws + 48 * MB);
    short* wT    = (short*)(ws + 64 * MB);
    float* stats = (float*)(ws + 66 * MB);
    float* ml    = (float*)(ws + 66 * MB + 65536);
    short* Opart = (short*)(ws + 67 * MB);
    char*  vT8   = (char*)(ws + 99 * MB);
    char*  q8    = (char*)ws;                       // overlays xn (dead by then)
    char*  k8    = q8 + (size_t)BATCH * SEQ * CH;   // +8MB
    short* attn  = xn;                              // overlays q8/k8 (dead after flash)

    hipMemsetAsync(stats, 0, 256 * sizeof(float), stream);
    gn_partial_kernel<<<256, 256, 0, stream>>>(x, stats);
    gn_apply_kernel<<<8192, 256, 0, stream>>>(x, stats, gsc, gbs, xn);
    wtrans_kernel<<<dim3(16, 16, 4), dim3(32, 8), 0, stream>>>(wq, wk, wv, wo, wT);

    short* woT = wT + 786432;

    gemm_qkv_kernel<<<dim3(128, 12), 256, 0, stream>>>(xn, wT, bq, bk, bv, qb);
    // q,k bf16 (32MB contiguous at qb) -> fp8 into q8/k8 (over dead xn)
    convert_fp8_kernel<<<8192, 256, 0, stream>>>(qb, q8);
    vtrans_kernel<<<dim3(128, 16, 4), dim3(32, 8), 0, stream>>>(vraw, vT8);
    flash_kernel<<<dim3(32, 2, 4), 512, 0, stream>>>(q8, k8, vT8, Opart, ml);
    combine_kernel<<<4096, 256, 0, stream>>>(Opart, ml, attn);
    gemm_bt_kernel<<<dim3(128, 4), 256, 0, stream>>>(attn, woT, bo, out, x);
}

// Round 8
// 331.778 us; speedup vs baseline: 1.7942x; 1.0829x over previous
//
#include <hip/hip_runtime.h>
#include <hip/hip_bf16.h>
#include <stdint.h>

#define BATCH 4
#define SEQ   4096          // 64*64 spatial
#define CH    512
#define NGRP  32
#define GEPS  1e-6f

typedef short  short8  __attribute__((ext_vector_type(8)));
typedef float  floatx4 __attribute__((ext_vector_type(4)));

static __device__ __forceinline__ short bf16b(float f) {
    __hip_bfloat16 h = __float2bfloat16(f);
    return __builtin_bit_cast(short, h);
}
static __device__ __forceinline__ float bf2f(short s) {
    unsigned u = ((unsigned)(unsigned short)s) << 16;
    return __builtin_bit_cast(float, u);
}
static __device__ __forceinline__ char fp8b(float f) {
    int pk = __builtin_amdgcn_cvt_pk_fp8_f32(f, f, 0, false);
    return (char)(pk & 0xff);
}

// async global->LDS, 16B per lane. LDS dest = wave-uniform base + lane*16.
static __device__ __forceinline__ void dma16(const void* g, void* l) {
    __builtin_amdgcn_global_load_lds(
        (const __attribute__((address_space(1))) unsigned int*)g,
        (__attribute__((address_space(3))) unsigned int*)l, 16, 0, 0);
}

// max-reduce across the 16 lanes of a DPP row, pure VALU
static __device__ __forceinline__ float rowmax16(float x) {
    int xi = __builtin_bit_cast(int, x);
    x = fmaxf(x, __builtin_bit_cast(float, __builtin_amdgcn_update_dpp(xi, xi, 0x128, 0xf, 0xf, true))); // row_ror:8
    xi = __builtin_bit_cast(int, x);
    x = fmaxf(x, __builtin_bit_cast(float, __builtin_amdgcn_update_dpp(xi, xi, 0x124, 0xf, 0xf, true))); // row_ror:4
    xi = __builtin_bit_cast(int, x);
    x = fmaxf(x, __builtin_bit_cast(float, __builtin_amdgcn_update_dpp(xi, xi, 0x122, 0xf, 0xf, true))); // row_ror:2
    xi = __builtin_bit_cast(int, x);
    x = fmaxf(x, __builtin_bit_cast(float, __builtin_amdgcn_update_dpp(xi, xi, 0x121, 0xf, 0xf, true))); // row_ror:1
    return x;
}

// ---------------- GroupNorm partial sums ----------------
__global__ __launch_bounds__(256) void gn_partial_kernel(const float* __restrict__ x,
                                                         float* __restrict__ statsraw) {
    int blk = blockIdx.x;                 // 0..255
    int t = threadIdx.x;
    size_t row0 = (size_t)blk * 64;
    int qd = t & 127;
    int rh = t >> 7;
    const float* base = x + row0 * 512 + qd * 4;
    float s1 = 0.f, s2 = 0.f;
    #pragma unroll 4
    for (int i = 0; i < 32; ++i) {
        int r = rh + i * 2;
        float4 v = *reinterpret_cast<const float4*>(base + (size_t)r * 512);
        s1 += v.x + v.y + v.z + v.w;
        s2 += v.x * v.x + v.y * v.y + v.z * v.z + v.w * v.w;
    }
    __shared__ float a1[256], a2[256];
    a1[t] = s1; a2[t] = s2;
    __syncthreads();
    if (t < 32) {
        float u1 = 0.f, u2 = 0.f;
        #pragma unroll
        for (int e = 0; e < 4; ++e) {
            u1 += a1[t * 4 + e] + a1[128 + t * 4 + e];
            u2 += a2[t * 4 + e] + a2[128 + t * 4 + e];
        }
        int b = (int)(row0 >> 12);
        atomicAdd(&statsraw[(b * 32 + t) * 2],     u1);
        atomicAdd(&statsraw[(b * 32 + t) * 2 + 1], u2);
    }
}

// ---------------- GroupNorm apply ----------------
__global__ __launch_bounds__(256) void gn_apply_kernel(const float* __restrict__ x,
                                                       const float* __restrict__ statsraw,
                                                       const float* __restrict__ gsc,
                                                       const float* __restrict__ gbs,
                                                       short* __restrict__ xn) {
    int i4 = blockIdx.x * 256 + threadIdx.x;
    int base = i4 * 4;
    int b = base >> 21;
    int c = base & 511;
    int sidx = (b * 32 + (c >> 4)) * 2;
    float s1 = statsraw[sidx], s2 = statsraw[sidx + 1];
    float mean = s1 * (1.f / 65536.f);
    float var  = s2 * (1.f / 65536.f) - mean * mean;
    float rstd = rsqrtf(var + GEPS);
    float4 xv = reinterpret_cast<const float4*>(x)[i4];
    float4 sv = *reinterpret_cast<const float4*>(gsc + c);
    float4 bv = *reinterpret_cast<const float4*>(gbs + c);
    union { short s[4]; uint2 u; } p;
    p.s[0] = bf16b((xv.x - mean) * rstd * sv.x + bv.x);
    p.s[1] = bf16b((xv.y - mean) * rstd * sv.y + bv.y);
    p.s[2] = bf16b((xv.z - mean) * rstd * sv.z + bv.z);
    p.s[3] = bf16b((xv.w - mean) * rstd * sv.w + bv.w);
    reinterpret_cast<uint2*>(xn)[i4] = p.u;
}

// ---------------- weight transpose ----------------
__global__ __launch_bounds__(256) void wtrans_kernel(const float* __restrict__ w0,
                                                     const float* __restrict__ w1,
                                                     const float* __restrict__ w2,
                                                     const float* __restrict__ w3,
                                                     short* __restrict__ wT) {
    const float* w = (blockIdx.z == 0) ? w0 : (blockIdx.z == 1) ? w1
                   : (blockIdx.z == 2) ? w2 : w3;
    short* out = wT + (size_t)blockIdx.z * CH * CH;
    int n0 = blockIdx.x * 32, k0 = blockIdx.y * 32;
    int tx = threadIdx.x, ty = threadIdx.y;
    __shared__ float s[32][33];
    #pragma unroll
    for (int i = 0; i < 4; ++i) {
        int kk = ty + i * 8;
        s[kk][tx] = w[(size_t)(k0 + kk) * CH + n0 + tx];
    }
    __syncthreads();
    #pragma unroll
    for (int i = 0; i < 4; ++i) {
        int nn = ty + i * 8;
        out[(size_t)(n0 + nn) * CH + k0 + tx] = bf16b(s[tx][nn]);
    }
}

// ---------------- fused QKV GEMM: fp8 epilogue (q8/k8 row-major, v transposed) -------
__global__ __launch_bounds__(256) void gemm_qkv_kernel(const short* __restrict__ A,
                                                       const short* __restrict__ wT,
                                                       const float* __restrict__ bq,
                                                       const float* __restrict__ bk,
                                                       const float* __restrict__ bv,
                                                       char* __restrict__ q8,
                                                       char* __restrict__ k8,
                                                       char* __restrict__ vT8) {
    __shared__ short As[128 * 64];
    __shared__ short Bs[128 * 64];
    int m0 = blockIdx.x * 128;
    int nblk = blockIdx.y;                  // 0..11
    int which = nblk >> 2;                  // 0=q,1=k,2=v (block-uniform)
    int n0 = (nblk & 3) * 128;
    const short* BT = wT + (size_t)which * 512 * 512;
    const float* bias = (which == 0) ? bq : (which == 1) ? bk : bv;
    int t = threadIdx.x;
    int w = t >> 6, lane = t & 63;
    int wr = w >> 1, wc = w & 1;
    int l15 = lane & 15, l4 = lane >> 4;
    floatx4 acc[4][4];
    #pragma unroll
    for (int i = 0; i < 4; ++i)
        #pragma unroll
        for (int j = 0; j < 4; ++j) acc[i][j] = (floatx4){0.f, 0.f, 0.f, 0.f};

    for (int k0 = 0; k0 < 512; k0 += 64) {
        __syncthreads();
        #pragma unroll
        for (int i = 0; i < 4; ++i) {
            int c = i * 256 + t;
            int row = c >> 3, j = (c & 7) ^ (row & 7);
            dma16(&A[(size_t)(m0 + row) * 512 + k0 + j * 8], &As[(c & ~63) * 8]);
            dma16(&BT[(size_t)(n0 + row) * 512 + k0 + j * 8], &Bs[(c & ~63) * 8]);
        }
        __syncthreads();
        #pragma unroll
        for (int kk = 0; kk < 64; kk += 32) {
            short8 af[4], bf[4];
            #pragma unroll
            for (int i = 0; i < 4; ++i) {
                int row = wr * 64 + i * 16 + l15;
                int j = (kk >> 3) + l4;
                af[i] = *reinterpret_cast<const short8*>(&As[(row * 8 + (j ^ (l15 & 7))) * 8]);
            }
            #pragma unroll
            for (int j2 = 0; j2 < 4; ++j2) {
                int row = wc * 64 + j2 * 16 + l15;
                int j = (kk >> 3) + l4;
                bf[j2] = *reinterpret_cast<const short8*>(&Bs[(row * 8 + (j ^ (l15 & 7))) * 8]);
            }
            #pragma unroll
            for (int i = 0; i < 4; ++i)
                #pragma unroll
                for (int j2 = 0; j2 < 4; ++j2)
                    acc[i][j2] = __builtin_amdgcn_mfma_f32_16x16x32_bf16(af[i], bf[j2], acc[i][j2], 0, 0, 0);
        }
    }
    if (which < 2) {
        char* o8 = (which == 0) ? q8 : k8;
        #pragma unroll
        for (int i = 0; i < 4; ++i)
            #pragma unroll
            for (int j = 0; j < 4; ++j)
                #pragma unroll
                for (int r = 0; r < 4; ++r) {
                    int row = m0 + wr * 64 + i * 16 + l4 * 4 + r;
                    int col = n0 + wc * 64 + j * 16 + l15;
                    o8[(size_t)row * 512 + col] = fp8b(acc[i][j][r] + bias[col]);
                }
    } else {
        #pragma unroll
        for (int i = 0; i < 4; ++i)
            #pragma unroll
            for (int j = 0; j < 4; ++j)
                #pragma unroll
                for (int r = 0; r < 4; ++r) {
                    int row = m0 + wr * 64 + i * 16 + l4 * 4 + r;   // b*4096 + l
                    int col = n0 + wc * 64 + j * 16 + l15;          // d
                    int b = row >> 12, l = row & 4095;
                    vT8[((size_t)b * 512 + col) * 4096 + l] = fp8b(acc[i][j][r] + bias[col]);
                }
    }
}

// ---------------- output GEMM: bias + residual, fp32 out ----------------
__global__ __launch_bounds__(256) void gemm_bt_kernel(const short* __restrict__ A,
                                                      const short* __restrict__ BT,
                                                      const float* __restrict__ bias,
                                                      float* __restrict__ outf,
                                                      const float* __restrict__ resid) {
    __shared__ short As[128 * 64];
    __shared__ short Bs[128 * 64];
    int m0 = blockIdx.x * 128, n0 = blockIdx.y * 128;
    int t = threadIdx.x;
    int w = t >> 6, lane = t & 63;
    int wr = w >> 1, wc = w & 1;
    int l15 = lane & 15, l4 = lane >> 4;
    floatx4 acc[4][4];
    #pragma unroll
    for (int i = 0; i < 4; ++i)
        #pragma unroll
        for (int j = 0; j < 4; ++j) acc[i][j] = (floatx4){0.f, 0.f, 0.f, 0.f};

    for (int k0 = 0; k0 < 512; k0 += 64) {
        __syncthreads();
        #pragma unroll
        for (int i = 0; i < 4; ++i) {
            int c = i * 256 + t;
            int row = c >> 3, j = (c & 7) ^ (row & 7);
            dma16(&A[(size_t)(m0 + row) * 512 + k0 + j * 8], &As[(c & ~63) * 8]);
            dma16(&BT[(size_t)(n0 + row) * 512 + k0 + j * 8], &Bs[(c & ~63) * 8]);
        }
        __syncthreads();
        #pragma unroll
        for (int kk = 0; kk < 64; kk += 32) {
            short8 af[4], bf[4];
            #pragma unroll
            for (int i = 0; i < 4; ++i) {
                int row = wr * 64 + i * 16 + l15;
                int j = (kk >> 3) + l4;
                af[i] = *reinterpret_cast<const short8*>(&As[(row * 8 + (j ^ (l15 & 7))) * 8]);
            }
            #pragma unroll
            for (int j2 = 0; j2 < 4; ++j2) {
                int row = wc * 64 + j2 * 16 + l15;
                int j = (kk >> 3) + l4;
                bf[j2] = *reinterpret_cast<const short8*>(&Bs[(row * 8 + (j ^ (l15 & 7))) * 8]);
            }
            #pragma unroll
            for (int i = 0; i < 4; ++i)
                #pragma unroll
                for (int j2 = 0; j2 < 4; ++j2)
                    acc[i][j2] = __builtin_amdgcn_mfma_f32_16x16x32_bf16(af[i], bf[j2], acc[i][j2], 0, 0, 0);
        }
    }
    #pragma unroll
    for (int i = 0; i < 4; ++i)
        #pragma unroll
        for (int j = 0; j < 4; ++j)
            #pragma unroll
            for (int r = 0; r < 4; ++r) {
                int row = m0 + wr * 64 + i * 16 + l4 * 4 + r;
                int col = n0 + wc * 64 + j * 16 + l15;
                float vv = acc[i][j][r] + bias[col];
                outf[(size_t)row * 512 + col] = vv + resid[(size_t)row * 512 + col];
            }
}

// ---------------- flash attention: fp8, pipelined dbuf, 4 waves, 2 blocks/CU -------
// q8[b][l][d], k8[b][s][d], v8[b][d][s] all e4m3. S/softmax/O fp32, Opart bf16.
// LDS: K buf0 [0,16K) buf1 [16K,32K); V buf0 [32K,48K) buf1 [48K,64K); P [64K,64K+2560).
// One barrier per iter; DMA(i+1) issued before compute(i). Lazy rescale (margin 5).
__global__ __launch_bounds__(256, 2) void flash_kernel(const char* __restrict__ q8,
                                                       const char* __restrict__ k8,
                                                       const char* __restrict__ v8,
                                                       short* __restrict__ Opart,
                                                       float* __restrict__ ml) {
    __shared__ __align__(16) char smem[68096];
    int b = blockIdx.z;
    int part = blockIdx.y;
    int q0 = blockIdx.x * 64;
    int t = threadIdx.x, w = t >> 6, lane = t & 63;
    int l15 = lane & 15, l4 = lane >> 4;
    const float scale = 0.044194173824159216f;  // 1/sqrt(512)

    // Q fp8 fragments: rows w*16 + l15, all 512 k (8 B per ks-step)
    long qf[16];
    {
        const char* qrow = q8 + ((size_t)b * SEQ + q0 + w * 16 + l15) * 512;
        #pragma unroll
        for (int ks = 0; ks < 16; ++ks)
            qf[ks] = *reinterpret_cast<const long*>(qrow + ks * 32 + l4 * 8);
    }

    floatx4 acc[32];
    #pragma unroll
    for (int i = 0; i < 32; ++i) acc[i] = (floatx4){0.f, 0.f, 0.f, 0.f};
    floatx4 lacc = (floatx4){0.f, 0.f, 0.f, 0.f};
    float mused[4] = {-1e30f, -1e30f, -1e30f, -1e30f};

    const long ones = 0x3838383838383838L;   // e4m3 1.0 x8

    const char* kbase = k8 + (size_t)b * SEQ * 512;
    const char* vbase = v8 + (size_t)b * 512 * SEQ;

    const int kswz = l15 & 7;
    const int vswz = (l4 >> 1) ^ ((l15 >> 2) & 1);
    const int koff = (l4 & 1) * 8;
    const int s_begin = part * (SEQ / 2);

    // stage: K tile 32x512B (1024 chunks), V tile 512x32B (1024 chunks); 256 thr -> 4+4 dma16
    auto stage = [&](int s0, int buf) {
        char* Kd = smem + buf * 16384;
        char* Vd = smem + 32768 + buf * 16384;
        #pragma unroll
        for (int i = 0; i < 4; ++i) {
            int c = i * 256 + t;
            int row = c >> 5, j = (c & 31) ^ (row & 7);
            dma16(kbase + (size_t)(s0 + row) * 512 + j * 16, Kd + (size_t)(c & ~63) * 16);
        }
        #pragma unroll
        for (int i = 0; i < 4; ++i) {
            int c = i * 256 + t;
            int d = c >> 1, j = (c & 1) ^ ((d >> 2) & 1);
            dma16(vbase + (size_t)d * SEQ + s0 + j * 16, Vd + (size_t)(c & ~63) * 16);
        }
    };

    stage(s_begin, 0);
    __syncthreads();                                   // tile 0 ready

    for (int it = 0; it < 64; ++it) {
        int cur = it & 1;
        if (it + 1 < 64) stage(s_begin + (it + 1) * 32, 1 - cur);

        const char* Kb = smem + cur * 16384;
        const char* Vb = smem + 32768 + cur * 16384;

        // --- QK^T (fp8): S[16 rows][32 cols] in two 16x16 C-tiles
        floatx4 sa0 = (floatx4){0.f, 0.f, 0.f, 0.f};
        floatx4 sa1 = (floatx4){0.f, 0.f, 0.f, 0.f};
        #pragma unroll
        for (int ks = 0; ks < 16; ++ks) {
            int jc = ks * 2 + (l4 >> 1);
            int a0 = (l15 * 32 + (jc ^ kswz)) * 16 + koff;
            long b0 = *reinterpret_cast<const long*>(Kb + a0);
            long b1 = *reinterpret_cast<const long*>(Kb + a0 + 8192);
            sa0 = __builtin_amdgcn_mfma_f32_16x16x32_fp8_fp8(qf[ks], b0, sa0, 0, 0, 0);
            sa1 = __builtin_amdgcn_mfma_f32_16x16x32_fp8_fp8(qf[ks], b1, sa1, 0, 0, 0);
        }

        // --- online softmax with lazy rescale: rescale only when max drifts > 5
        float v0[4], v1[4], nm4[4];
        bool need = false;
        #pragma unroll
        for (int r = 0; r < 4; ++r) {
            v0[r] = sa0[r] * scale; v1[r] = sa1[r] * scale;
            nm4[r] = rowmax16(fmaxf(v0[r], v1[r]));
            need |= (nm4[r] > mused[r] + 5.0f);
        }
        if (__ballot(need)) {
            #pragma unroll
            for (int r = 0; r < 4; ++r) {
                float nm = fmaxf(mused[r], nm4[r]);
                float al = __expf(mused[r] - nm);
                lacc[r] *= al;
                #pragma unroll
                for (int i = 0; i < 32; ++i) acc[i][r] *= al;
                mused[r] = nm;
            }
        }
        float p0[4], p1[4];
        #pragma unroll
        for (int r = 0; r < 4; ++r) {
            p0[r] = __expf(v0[r] - mused[r]);     // <= e^5 = 148 < 448 fp8 max
            p1[r] = __expf(v1[r] - mused[r]);
        }

        // P (fp8) write to wave-private region (pitch 40 B)
        char* Ps = smem + 65536 + w * 640;
        #pragma unroll
        for (int r = 0; r < 4; ++r) {
            int pk = __builtin_amdgcn_cvt_pk_fp8_f32(p0[r], p1[r], 0, false);
            Ps[(l4 * 4 + r) * 40 + l15]      = (char)(pk & 0xff);
            Ps[(l4 * 4 + r) * 40 + 16 + l15] = (char)((pk >> 8) & 0xff);
        }

        long pf = *reinterpret_cast<const long*>(Ps + l15 * 40 + l4 * 8);
        lacc = __builtin_amdgcn_mfma_f32_16x16x32_fp8_fp8(pf, ones, lacc, 0, 0, 0);
        #pragma unroll
        for (int tt = 0; tt < 32; ++tt) {
            int d = tt * 16 + l15;
            long vf = *reinterpret_cast<const long*>(Vb + (d * 2 + vswz) * 16 + koff);
            acc[tt] = __builtin_amdgcn_mfma_f32_16x16x32_fp8_fp8(pf, vf, acc[tt], 0, 0, 0);
        }

        __syncthreads();    // drains DMA(i+1) + all reads of buf[cur] done
    }

    short* obase = Opart + (((size_t)part * BATCH + b) * SEQ + q0 + w * 16) * 512;
    #pragma unroll
    for (int r = 0; r < 4; ++r) {
        #pragma unroll
        for (int tt = 0; tt < 32; ++tt)
            obase[(size_t)(l4 * 4 + r) * 512 + tt * 16 + l15] = bf16b(acc[tt][r]);
    }
    if (l15 == 0) {
        #pragma unroll
        for (int r = 0; r < 4; ++r) {
            size_t rowg = ((size_t)part * BATCH + b) * SEQ + q0 + w * 16 + l4 * 4 + r;
            ml[rowg * 2]     = mused[r];
            ml[rowg * 2 + 1] = lacc[r];
        }
    }
}

// ---------------- combine ----------------
__global__ __launch_bounds__(256) void combine_kernel(const short* __restrict__ Opart,
                                                      const float* __restrict__ ml,
                                                      short* __restrict__ attn) {
    int i8 = blockIdx.x * 256 + threadIdx.x;
    size_t row = (size_t)i8 >> 6;
    float m0 = ml[row * 2], l0 = ml[row * 2 + 1];
    float m1 = ml[((size_t)BATCH * SEQ + row) * 2], l1 = ml[((size_t)BATCH * SEQ + row) * 2 + 1];
    float m = fmaxf(m0, m1);
    float e0 = __expf(m0 - m), e1 = __expf(m1 - m);
    float inv = 1.f / (e0 * l0 + e1 * l1);
    e0 *= inv; e1 *= inv;
    union { uint4 u; short s[8]; } a, bb, o;
    a.u  = reinterpret_cast<const uint4*>(Opart)[i8];
    bb.u = reinterpret_cast<const uint4*>(Opart)[(size_t)BATCH * SEQ * 512 / 8 + i8];
    #pragma unroll
    for (int e = 0; e < 8; ++e)
        o.s[e] = bf16b(bf2f(a.s[e]) * e0 + bf2f(bb.s[e]) * e1);
    reinterpret_cast<uint4*>(attn)[i8] = o.u;
}

extern "C" void kernel_launch(void* const* d_in, const int* in_sizes, int n_in,
                              void* d_out, int out_size, void* d_ws, size_t ws_size,
                              hipStream_t stream) {
    const float* x   = (const float*)d_in[0];
    const float* gsc = (const float*)d_in[1];
    const float* gbs = (const float*)d_in[2];
    const float* wq  = (const float*)d_in[3];
    const float* bq  = (const float*)d_in[4];
    const float* wk  = (const float*)d_in[5];
    const float* bk  = (const float*)d_in[6];
    const float* wv  = (const float*)d_in[7];
    const float* bv  = (const float*)d_in[8];
    const float* wo  = (const float*)d_in[9];
    const float* bo  = (const float*)d_in[10];
    float* out = (float*)d_out;

    char* ws = (char*)d_ws;
    const size_t MB = 1ull << 20;
    // [0,16)  xn bf16 (GEMM A input); attn bf16 overlays after QKV GEMM (xn dead)
    // [16,24) q8; [24,32) k8; [32,40) vT8  (fp8, written by gemm_qkv epilogue)
    // [40,72) Opart bf16; [72,74) wT; [74,..) stats + ml
    short* xn    = (short*)ws;
    char*  q8    = (char*)(ws + 16 * MB);
    char*  k8    = (char*)(ws + 24 * MB);
    char*  vT8   = (char*)(ws + 32 * MB);
    short* Opart = (short*)(ws + 40 * MB);
    short* wT    = (short*)(ws + 72 * MB);
    float* stats = (float*)(ws + 74 * MB);
    float* ml    = (float*)(ws + 74 * MB + 65536);
    short* attn  = xn;

    hipMemsetAsync(stats, 0, 256 * sizeof(float), stream);
    gn_partial_kernel<<<256, 256, 0, stream>>>(x, stats);
    gn_apply_kernel<<<8192, 256, 0, stream>>>(x, stats, gsc, gbs, xn);
    wtrans_kernel<<<dim3(16, 16, 4), dim3(32, 8), 0, stream>>>(wq, wk, wv, wo, wT);

    short* woT = wT + 786432;

    gemm_qkv_kernel<<<dim3(128, 12), 256, 0, stream>>>(xn, wT, bq, bk, bv, q8, k8, vT8);
    flash_kernel<<<dim3(64, 2, 4), 256, 0, stream>>>(q8, k8, vT8, Opart, ml);
    combine_kernel<<<4096, 256, 0, stream>>>(Opart, ml, attn);
    gemm_bt_kernel<<<dim3(128, 4), 256, 0, stream>>>(attn, woT, bo, out, x);
}